// Round 1
// baseline (1482.133 us; speedup 1.0000x reference)
//
#include <hip/hip_runtime.h>
#include <math.h>

#define B 32
#define CIN 22
#define T 5000
#define EMB 64
#define P 100
#define HOP 25
#define OC 40
#define FC 120
#define NBIN 11   // rfft bins 5..15
#define NFR 200
#define XSROW 304

typedef unsigned short ushort_t;
struct __align__(8) US4 { unsigned short x, y, z, w; };

__device__ __forceinline__ unsigned short f2bf(float f) {
  unsigned u = __float_as_uint(f);
  unsigned r = (u + 0x7FFFu + ((u >> 16) & 1u)) >> 16;
  return (unsigned short)r;
}
__device__ __forceinline__ float bf2f(unsigned short u) {
  return __uint_as_float(((unsigned)u) << 16);
}

// ---------------- K1a: fuse conv1+conv2 weights per scale ----------------
__global__ void prep_scale(const float* __restrict__ w1, const float* __restrict__ b1,
                           const float* __restrict__ w2, const float* __restrict__ b2,
                           const float* __restrict__ g,  const float* __restrict__ bt,
                           const float* __restrict__ m,  const float* __restrict__ v,
                           int ks, int wbase, int abase,
                           float* __restrict__ W, float* __restrict__ A, float* __restrict__ Bc) {
  int nW = OC * CIN * ks;
  int id = blockIdx.x * 256 + threadIdx.x;
  if (id < nW) {
    int o = id / (CIN * ks);
    int rem = id - o * (CIN * ks);
    int h = rem / ks;
    int k = rem - h * ks;
    float s = 0.f;
    for (int i = 0; i < OC; ++i)
      s = fmaf(w2[(o * OC + i) * CIN + h], w1[i * ks + k], s);
    W[wbase + id] = s;
  } else if (id < nW + OC) {
    int o = id - nW;
    float sc = g[o] / sqrtf(v[o] + 1e-5f);
    float cc = b2[o];
    for (int i = 0; i < OC; ++i) {
      float sh = 0.f;
      for (int h = 0; h < CIN; ++h) sh += w2[(o * OC + i) * CIN + h];
      cc = fmaf(b1[i], sh, cc);
    }
    A[abase + o] = sc;
    Bc[abase + o] = cc * sc + (bt[o] - m[o] * sc);
  }
}

// ---------------- K1b: windowed DFT twiddles for bins 5..15 ----------------
__global__ void twiddles(float* __restrict__ tcos, float* __restrict__ tsin) {
  int id = blockIdx.x * 256 + threadIdx.x;
  if (id >= NBIN * 128) return;
  int k = id / 128 + 5, n = id - (id / 128) * 128;
  const double PI = 3.14159265358979323846;
  double ang = -2.0 * PI * (double)(k * n) / 128.0;
  double win = 0.5 * (1.0 - cos(2.0 * PI * (double)n / 128.0));
  tcos[id] = (float)(cos(ang) * win);
  tsin[id] = (float)(sin(ang) * win);
}

// ---------------- K2: STFT power -> comb (mu mean + beta mean) ----------------
__global__ __launch_bounds__(256) void stft_comb(const float* __restrict__ x,
                                                 const float* __restrict__ tcg,
                                                 const float* __restrict__ tsg,
                                                 float* __restrict__ comb) {
  __shared__ float tc[NBIN * 128];
  __shared__ float ts[NBIN * 128];
  for (int i = threadIdx.x; i < NBIN * 128; i += 256) { tc[i] = tcg[i]; ts[i] = tsg[i]; }
  __syncthreads();
  int id = blockIdx.x * 256 + threadIdx.x;
  if (id >= B * CIN * NFR) return;
  int fr = id % NFR;
  int bc = id / NFR;
  const float* xr = x + (size_t)bc * T;
  float cr[NBIN], ci[NBIN];
  #pragma unroll
  for (int k = 0; k < NBIN; ++k) { cr[k] = 0.f; ci[k] = 0.f; }
  int base = fr * HOP - 64;
  for (int n = 0; n < 128; ++n) {
    int mm = base + n;
    mm = (mm < 0) ? -mm : mm;
    mm = (mm >= T) ? (2 * T - 2 - mm) : mm;
    float xv = xr[mm];
    #pragma unroll
    for (int k = 0; k < NBIN; ++k) {
      cr[k] = fmaf(xv, tc[k * 128 + n], cr[k]);
      ci[k] = fmaf(xv, ts[k * 128 + n], ci[k]);
    }
  }
  float p[NBIN];
  #pragma unroll
  for (int k = 0; k < NBIN; ++k) p[k] = cr[k] * cr[k] + ci[k] * ci[k];
  float beta = 0.f;
  #pragma unroll
  for (int k = 2; k < NBIN; ++k) beta += p[k];
  comb[id] = 0.5f * (p[0] + p[1]) + beta * (1.f / 9.f);
}

// ---------------- K3: activity conv + sigmoid + interp + adaptive grid ----------------
__global__ __launch_bounds__(256) void act_grid(const float* __restrict__ comb,
    const float* __restrict__ aw1, const float* __restrict__ ab1,
    const float* __restrict__ ag,  const float* __restrict__ abt,
    const float* __restrict__ am,  const float* __restrict__ av,
    const float* __restrict__ aw2, const float* __restrict__ ab2,
    float* __restrict__ out_grid, float* __restrict__ out_acti,
    int* __restrict__ ends_i, int* __restrict__ grid_i) {
  int b = blockIdx.x;
  __shared__ float cl[CIN * NFR];
  __shared__ float actL[NFR];
  __shared__ float aiL[P];
  __shared__ int gridL[P];
  __shared__ int endsL[P];
  for (int i = threadIdx.x; i < CIN * NFR; i += 256) cl[i] = comb[b * CIN * NFR + i];
  __syncthreads();
  int t = threadIdx.x;
  if (t < NFR) {
    float z = ab2[0];
    for (int o = 0; o < 11; ++o) {
      float s = ab1[o];
      for (int i = 0; i < CIN; ++i) {
        const float* wr = aw1 + o * 66 + i * 3;
        const float* crow = cl + i * NFR;
        if (t > 0)       s = fmaf(wr[0], crow[t - 1], s);
        s = fmaf(wr[1], crow[t], s);
        if (t < NFR - 1) s = fmaf(wr[2], crow[t + 1], s);
      }
      float rs = 1.0f / sqrtf(av[o] + 1e-5f);
      float y = (s - am[o]) * rs * ag[o] + abt[o];
      y = fmaxf(y, 0.f);
      z = fmaf(aw2[o], y, z);
    }
    actL[t] = 1.f / (1.f + expf(-z));
  }
  __syncthreads();
  if (t < P) {
    float ai = 0.5f * (actL[2 * t] + actL[2 * t + 1]);
    aiL[t] = ai;
    out_acti[b * P + t] = ai;
  }
  __syncthreads();
  if (t == 0) {
    float w[P], gs[P];
    float sw = 0.f;
    for (int p = 0; p < P; ++p) { w[p] = 1.f / (aiL[p] + 1e-6f); sw += w[p]; }
    float s2 = 0.f;
    for (int p = 0; p < P; ++p) {
      float gg = (w[p] / sw) * 5000.f;
      gg = fminf(fmaxf(gg, 10.f), 100.f);
      gs[p] = gg; s2 += gg;
    }
    float r = 5000.f / s2;
    int gi[P];
    int s3 = 0;
    for (int p = 0; p < P; ++p) { gi[p] = (int)rintf(gs[p] * r); s3 += gi[p]; }
    gi[P - 1] += 5000 - s3;
    int s4 = 0;
    for (int p = 0; p < P; ++p) { int vv = min(max(gi[p], 10), 100); gi[p] = vv; s4 += vv; }
    gi[P - 1] += 5000 - s4;
    int e = 0;
    for (int p = 0; p < P; ++p) {
      int vv = gi[p] < 10 ? 10 : gi[p];
      gridL[p] = vv; e += vv; endsL[p] = e;
    }
  }
  __syncthreads();
  if (t < P) {
    out_grid[b * P + t] = (float)gridL[t];
    ends_i[b * P + t] = endsL[t];
    grid_i[b * P + t] = gridL[t];
  }
}

// ---------------- K4: fused multi-scale conv -> bf16 feats ----------------
template <int KS>
__device__ __forceinline__ void conv_scale(const float* __restrict__ Wc,
                                           const float* __restrict__ xs, int lane,
                                           float& a0, float& a1, float& a2, float& a3) {
  constexpr int PAD = (KS - 1) / 2;
  constexpr int M = (KS - 1) / 4;  // KS = 4M+1
  const int j0 = 4 * lane + (24 - PAD);   // 16B aligned (24-PAD multiple of 4)
  for (int h = 0; h < CIN; ++h) {
    const float4* r = reinterpret_cast<const float4*>(xs + h * XSROW + j0);
    const float* Wh = Wc + h * KS;
    float4 cur = r[0];
    #pragma unroll
    for (int q = 0; q < M; ++q) {
      float4 nxt = r[q + 1];
      float w0 = Wh[4 * q], w1 = Wh[4 * q + 1], w2 = Wh[4 * q + 2], w3 = Wh[4 * q + 3];
      a0 = fmaf(w0, cur.x, a0); a1 = fmaf(w0, cur.y, a1); a2 = fmaf(w0, cur.z, a2); a3 = fmaf(w0, cur.w, a3);
      a0 = fmaf(w1, cur.y, a0); a1 = fmaf(w1, cur.z, a1); a2 = fmaf(w1, cur.w, a2); a3 = fmaf(w1, nxt.x, a3);
      a0 = fmaf(w2, cur.z, a0); a1 = fmaf(w2, cur.w, a1); a2 = fmaf(w2, nxt.x, a2); a3 = fmaf(w2, nxt.y, a3);
      a0 = fmaf(w3, cur.w, a0); a1 = fmaf(w3, nxt.x, a1); a2 = fmaf(w3, nxt.y, a2); a3 = fmaf(w3, nxt.z, a3);
      cur = nxt;
    }
    float wl = Wh[KS - 1];
    a0 = fmaf(wl, cur.x, a0); a1 = fmaf(wl, cur.y, a1); a2 = fmaf(wl, cur.z, a2); a3 = fmaf(wl, cur.w, a3);
  }
}

__global__ __launch_bounds__(256) void conv_feats(const float* __restrict__ x,
                                                  const float* __restrict__ Wall,
                                                  const float* __restrict__ Aff,
                                                  const float* __restrict__ Bff,
                                                  unsigned short* __restrict__ feats) {
  int tile = blockIdx.x, b = blockIdx.y;
  int t0 = tile * 256;
  __shared__ float xs[CIN * XSROW];
  for (int idx = threadIdx.x; idx < CIN * XSROW; idx += 256) {
    int h = idx / XSROW, j = idx - h * XSROW;
    int gt = t0 - 24 + j;
    xs[idx] = (gt >= 0 && gt < T) ? x[(size_t)(b * CIN + h) * T + gt] : 0.f;
  }
  __syncthreads();
  int wv = threadIdx.x >> 6, lane = threadIdx.x & 63;
  int tb = t0 + 4 * lane;
  bool full = (tb + 3 < T);
  for (int j = 0; j < 30; ++j) {
    int ch = __builtin_amdgcn_readfirstlane(wv + 4 * j);  // wave-uniform channel -> s_loads for W
    float a0 = 0.f, a1 = 0.f, a2 = 0.f, a3 = 0.f;
    if (ch < 40)
      conv_scale<9>(Wall + ch * (CIN * 9), xs, lane, a0, a1, a2, a3);
    else if (ch < 80)
      conv_scale<25>(Wall + 7920 + (ch - 40) * (CIN * 25), xs, lane, a0, a1, a2, a3);
    else
      conv_scale<49>(Wall + 29920 + (ch - 80) * (CIN * 49), xs, lane, a0, a1, a2, a3);
    float A = Aff[ch], Bv = Bff[ch];
    float y0 = fmaf(a0, A, Bv), y1 = fmaf(a1, A, Bv), y2 = fmaf(a2, A, Bv), y3 = fmaf(a3, A, Bv);
    float e0 = y0 > 0.f ? y0 : expm1f(y0);
    float e1 = y1 > 0.f ? y1 : expm1f(y1);
    float e2 = y2 > 0.f ? y2 : expm1f(y2);
    float e3 = y3 > 0.f ? y3 : expm1f(y3);
    size_t off = (size_t)(b * FC + ch) * T + tb;
    if (full) {
      US4 pk; pk.x = f2bf(e0); pk.y = f2bf(e1); pk.z = f2bf(e2); pk.w = f2bf(e3);
      *reinterpret_cast<US4*>(feats + off) = pk;
    } else {
      if (tb < T)     feats[off]     = f2bf(e0);
      if (tb + 1 < T) feats[off + 1] = f2bf(e1);
      if (tb + 2 < T) feats[off + 2] = f2bf(e2);
      if (tb + 3 < T) feats[off + 3] = f2bf(e3);
    }
  }
}

// ---------------- K5: ragged avg+max pool + projection ----------------
__global__ __launch_bounds__(128) void pool_proj(const unsigned short* __restrict__ feats,
                                                 const int* __restrict__ ends_i,
                                                 const int* __restrict__ grid_i,
                                                 const float* __restrict__ proj_w,
                                                 const float* __restrict__ proj_b,
                                                 float* __restrict__ out_emb) {
  int bp = blockIdx.x;
  int b = bp / P;
  int end = ends_i[bp];
  int gr = grid_i[bp];
  int start = end - gr;
  __shared__ float pooled[FC];
  bool valid = (end <= T);
  int wv = threadIdx.x >> 6, lane = threadIdx.x & 63;
  if (valid) {
    for (int ch = wv; ch < FC; ch += 2) {
      const unsigned short* row = feats + (size_t)(b * FC + ch) * T;
      float s = 0.f, mx = -INFINITY;
      for (int tt = start + lane; tt < end; tt += 64) {
        float v = bf2f(row[tt]);
        s += v;
        mx = fmaxf(mx, v);
      }
      #pragma unroll
      for (int off = 1; off < 64; off <<= 1) {
        s += __shfl_xor(s, off);
        mx = fmaxf(mx, __shfl_xor(mx, off));
      }
      if (lane == 0) pooled[ch] = s / (float)gr + mx;
    }
  } else {
    for (int ch = threadIdx.x; ch < FC; ch += 128) pooled[ch] = 0.f;
  }
  __syncthreads();
  int o = threadIdx.x;
  if (o < EMB) {
    float e = proj_b[o];
    for (int c = 0; c < FC; ++c) e = fmaf(proj_w[o * FC + c], pooled[c], e);
    out_emb[(size_t)bp * EMB + o] = e;
  }
}

extern "C" void kernel_launch(void* const* d_in, const int* in_sizes, int n_in,
                              void* d_out, int out_size, void* d_ws, size_t ws_size,
                              hipStream_t stream) {
  const float* x = (const float*)d_in[0];
  // ms{i}: w1,b1,w2,b2,g,bt,m,v at 1+8i..8+8i
  const float* aw1 = (const float*)d_in[25];
  const float* ab1 = (const float*)d_in[26];
  const float* ag  = (const float*)d_in[27];
  const float* abt = (const float*)d_in[28];
  const float* am  = (const float*)d_in[29];
  const float* av  = (const float*)d_in[30];
  const float* aw2 = (const float*)d_in[31];
  const float* ab2 = (const float*)d_in[32];
  const float* proj_w = (const float*)d_in[33];
  const float* proj_b = (const float*)d_in[34];

  float* wsf = (float*)d_ws;
  float* W    = wsf;                 // 73040
  float* A    = wsf + 73040;         // 120
  float* Bc   = wsf + 73160;         // 120
  float* tcs  = wsf + 73280;         // 1408
  float* tsn  = wsf + 74688;         // 1408
  float* comb = wsf + 76096;         // 140800
  int* ends_i = (int*)(wsf + 216896);       // 3200
  int* grid_i = (int*)(wsf + 220096);       // 3200
  unsigned short* feats = (unsigned short*)(wsf + 223296);  // 19.2M ushorts (38.4 MB)

  float* out      = (float*)d_out;
  float* out_emb  = out;             // 204800
  float* out_grid = out + 204800;    // 3200
  float* out_acti = out + 208000;    // 3200

  const int kss[3]   = {9, 25, 49};
  const int wbase[3] = {0, 7920, 29920};
  for (int s = 0; s < 3; ++s) {
    const float* w1 = (const float*)d_in[1 + 8 * s];
    const float* b1 = (const float*)d_in[2 + 8 * s];
    const float* w2 = (const float*)d_in[3 + 8 * s];
    const float* b2 = (const float*)d_in[4 + 8 * s];
    const float* g  = (const float*)d_in[5 + 8 * s];
    const float* bt = (const float*)d_in[6 + 8 * s];
    const float* m  = (const float*)d_in[7 + 8 * s];
    const float* v  = (const float*)d_in[8 + 8 * s];
    int n = OC * CIN * kss[s] + OC;
    prep_scale<<<(n + 255) / 256, 256, 0, stream>>>(w1, b1, w2, b2, g, bt, m, v,
                                                    kss[s], wbase[s], 40 * s, W, A, Bc);
  }
  twiddles<<<(NBIN * 128 + 255) / 256, 256, 0, stream>>>(tcs, tsn);
  stft_comb<<<(B * CIN * NFR) / 256, 256, 0, stream>>>(x, tcs, tsn, comb);
  act_grid<<<B, 256, 0, stream>>>(comb, aw1, ab1, ag, abt, am, av, aw2, ab2,
                                  out_grid, out_acti, ends_i, grid_i);
  conv_feats<<<dim3(20, B), 256, 0, stream>>>(x, W, A, Bc, feats);
  pool_proj<<<B * P, 128, 0, stream>>>(feats, ends_i, grid_i, proj_w, proj_b, out_emb);
}

// Round 2
// 755.621 us; speedup vs baseline: 1.9615x; 1.9615x over previous
//
#include <hip/hip_runtime.h>
#include <math.h>

#define B 32
#define CIN 22
#define T 5000
#define EMB 64
#define P 100
#define HOP 25
#define OC 40
#define FC 120
#define NBIN 11   // rfft bins 5..15
#define NFR 200

#define ROWS 304      // 256-t chunk + 24 halo each side
#define RSTRIDE 40    // ushorts per xs row (80 B = 20 dwords -> bank-balanced)

typedef unsigned short ushort_t;
typedef __attribute__((ext_vector_type(8))) short bf16x8;
typedef __attribute__((ext_vector_type(4))) float f32x4;

__device__ __forceinline__ unsigned short f2bf(float f) {
  unsigned u = __float_as_uint(f);
  unsigned r = (u + 0x7FFFu + ((u >> 16) & 1u)) >> 16;
  return (unsigned short)r;
}
__device__ __forceinline__ float bf2f(unsigned short u) {
  return __uint_as_float(((unsigned)u) << 16);
}

// ---------------- K1a: fuse conv1+conv2 weights per scale ----------------
__global__ void prep_scale(const float* __restrict__ w1, const float* __restrict__ b1,
                           const float* __restrict__ w2, const float* __restrict__ b2,
                           const float* __restrict__ g,  const float* __restrict__ bt,
                           const float* __restrict__ m,  const float* __restrict__ v,
                           int ks, int wbase, int abase,
                           float* __restrict__ W, float* __restrict__ A, float* __restrict__ Bc) {
  int nW = OC * CIN * ks;
  int id = blockIdx.x * 256 + threadIdx.x;
  if (id < nW) {
    int o = id / (CIN * ks);
    int rem = id - o * (CIN * ks);
    int h = rem / ks;
    int k = rem - h * ks;
    float s = 0.f;
    for (int i = 0; i < OC; ++i)
      s = fmaf(w2[(o * OC + i) * CIN + h], w1[i * ks + k], s);
    W[wbase + id] = s;
  } else if (id < nW + OC) {
    int o = id - nW;
    float sc = g[o] / sqrtf(v[o] + 1e-5f);
    float cc = b2[o];
    for (int i = 0; i < OC; ++i) {
      float sh = 0.f;
      for (int h = 0; h < CIN; ++h) sh += w2[(o * OC + i) * CIN + h];
      cc = fmaf(b1[i], sh, cc);
    }
    A[abase + o] = sc;
    Bc[abase + o] = cc * sc + (bt[o] - m[o] * sc);
  }
}

// ---------------- K1b: pack fused weights into MFMA A-fragment order ----------------
// frag layout per (k, ot): lane l holds A[m=l&15][kd=(l>>4)*8+j], j=0..7
// A[m][kd] = W[o=ot*16+m][h=kd][k]   (zero if h>=22 or o>=40)
__global__ void pack_w(const float* __restrict__ W, unsigned short* __restrict__ pw,
                       int KS, int wbase, int fragbase) {
  int id = blockIdx.x * 256 + threadIdx.x;
  if (id >= KS * 3 * 512) return;
  int fi = id >> 9;
  int rem = id & 511;
  int lane = rem >> 3, j = rem & 7;
  int k = fi / 3, ot = fi - k * 3;
  int m = lane & 15, h = ((lane >> 4) << 3) + j;
  int o = ot * 16 + m;
  float v = (h < CIN && o < OC) ? W[wbase + (o * CIN + h) * KS + k] : 0.f;
  pw[(size_t)(fragbase + fi) * 512 + rem] = f2bf(v);
}

// ---------------- K1c: windowed DFT twiddles for bins 5..15 ----------------
__global__ void twiddles(float* __restrict__ tcos, float* __restrict__ tsin) {
  int id = blockIdx.x * 256 + threadIdx.x;
  if (id >= NBIN * 128) return;
  int k = id / 128 + 5, n = id - (id / 128) * 128;
  const double PI = 3.14159265358979323846;
  double ang = -2.0 * PI * (double)(k * n) / 128.0;
  double win = 0.5 * (1.0 - cos(2.0 * PI * (double)n / 128.0));
  tcos[id] = (float)(cos(ang) * win);
  tsin[id] = (float)(sin(ang) * win);
}

// ---------------- K2: STFT power -> comb ----------------
__global__ __launch_bounds__(256) void stft_comb(const float* __restrict__ x,
                                                 const float* __restrict__ tcg,
                                                 const float* __restrict__ tsg,
                                                 float* __restrict__ comb) {
  __shared__ float tc[NBIN * 128];
  __shared__ float ts[NBIN * 128];
  for (int i = threadIdx.x; i < NBIN * 128; i += 256) { tc[i] = tcg[i]; ts[i] = tsg[i]; }
  __syncthreads();
  int id = blockIdx.x * 256 + threadIdx.x;
  if (id >= B * CIN * NFR) return;
  int fr = id % NFR;
  int bc = id / NFR;
  const float* xr = x + (size_t)bc * T;
  float cr[NBIN], ci[NBIN];
  #pragma unroll
  for (int k = 0; k < NBIN; ++k) { cr[k] = 0.f; ci[k] = 0.f; }
  int base = fr * HOP - 64;
  for (int n = 0; n < 128; ++n) {
    int mm = base + n;
    mm = (mm < 0) ? -mm : mm;
    mm = (mm >= T) ? (2 * T - 2 - mm) : mm;
    float xv = xr[mm];
    #pragma unroll
    for (int k = 0; k < NBIN; ++k) {
      cr[k] = fmaf(xv, tc[k * 128 + n], cr[k]);
      ci[k] = fmaf(xv, ts[k * 128 + n], ci[k]);
    }
  }
  float p[NBIN];
  #pragma unroll
  for (int k = 0; k < NBIN; ++k) p[k] = cr[k] * cr[k] + ci[k] * ci[k];
  float beta = 0.f;
  #pragma unroll
  for (int k = 2; k < NBIN; ++k) beta += p[k];
  comb[id] = 0.5f * (p[0] + p[1]) + beta * (1.f / 9.f);
}

// ---------------- K3: activity conv + sigmoid + interp + adaptive grid ----------------
__device__ __forceinline__ float wave_sum_f(float v) {
  #pragma unroll
  for (int off = 1; off < 64; off <<= 1) v += __shfl_xor(v, off);
  return v;
}
__device__ __forceinline__ int wave_sum_i(int v) {
  #pragma unroll
  for (int off = 1; off < 64; off <<= 1) v += __shfl_xor(v, off);
  return v;
}

__global__ __launch_bounds__(256) void act_grid(const float* __restrict__ comb,
    const float* __restrict__ aw1, const float* __restrict__ ab1,
    const float* __restrict__ ag,  const float* __restrict__ abt,
    const float* __restrict__ am,  const float* __restrict__ av,
    const float* __restrict__ aw2, const float* __restrict__ ab2,
    float* __restrict__ out_grid, float* __restrict__ out_acti,
    int* __restrict__ ends_i, int* __restrict__ grid_i) {
  int b = blockIdx.x;
  __shared__ float cl[CIN * NFR];
  __shared__ float actL[NFR];
  __shared__ float aiL[P];
  __shared__ float fL[P];
  __shared__ int   giL[P];
  __shared__ int   sI[P];
  __shared__ float red[1];
  for (int i = threadIdx.x; i < CIN * NFR; i += 256) cl[i] = comb[b * CIN * NFR + i];
  __syncthreads();
  int t = threadIdx.x;
  if (t < NFR) {
    float z = ab2[0];
    for (int o = 0; o < 11; ++o) {
      float s = ab1[o];
      for (int i = 0; i < CIN; ++i) {
        const float* wr = aw1 + o * 66 + i * 3;
        const float* crow = cl + i * NFR;
        if (t > 0)       s = fmaf(wr[0], crow[t - 1], s);
        s = fmaf(wr[1], crow[t], s);
        if (t < NFR - 1) s = fmaf(wr[2], crow[t + 1], s);
      }
      float rs = 1.0f / sqrtf(av[o] + 1e-5f);
      float y = (s - am[o]) * rs * ag[o] + abt[o];
      y = fmaxf(y, 0.f);
      z = fmaf(aw2[o], y, z);
    }
    actL[t] = 1.f / (1.f + expf(-z));
  }
  __syncthreads();
  if (t < P) {
    float ai = 0.5f * (actL[2 * t] + actL[2 * t + 1]);
    aiL[t] = ai;
    out_acti[b * P + t] = ai;
    fL[t] = 1.f / (ai + 1e-6f);
  }
  __syncthreads();
  // sum of weights
  if (t < 64) {
    float v = fL[t] + ((t + 64 < P) ? fL[t + 64] : 0.f);
    v = wave_sum_f(v);
    if (t == 0) red[0] = v;
  }
  __syncthreads();
  float sw = red[0];
  if (t < P) {
    float gg = (fL[t] / sw) * 5000.f;
    gg = fminf(fmaxf(gg, 10.f), 100.f);
    fL[t] = gg;
  }
  __syncthreads();
  if (t < 64) {
    float v = fL[t] + ((t + 64 < P) ? fL[t + 64] : 0.f);
    v = wave_sum_f(v);
    if (t == 0) red[0] = v;
  }
  __syncthreads();
  float r = 5000.f / red[0];
  if (t < P) giL[t] = (int)rintf(fL[t] * r);
  __syncthreads();
  if (t < 64) {
    int v = giL[t] + ((t + 64 < P) ? giL[t + 64] : 0);
    v = wave_sum_i(v);
    if (t == 0) red[0] = __int_as_float(v);
  }
  __syncthreads();
  if (t == P - 1) giL[P - 1] += 5000 - __float_as_int(red[0]);
  __syncthreads();
  if (t < P) giL[t] = min(max(giL[t], 10), 100);
  __syncthreads();
  if (t < 64) {
    int v = giL[t] + ((t + 64 < P) ? giL[t + 64] : 0);
    v = wave_sum_i(v);
    if (t == 0) red[0] = __int_as_float(v);
  }
  __syncthreads();
  if (t == P - 1) giL[P - 1] += 5000 - __float_as_int(red[0]);
  __syncthreads();
  if (t < P) sI[t] = max(giL[t], 10);
  __syncthreads();
  // inclusive scan (Hillis-Steele) for ends
  #pragma unroll
  for (int off = 1; off < P; off <<= 1) {
    int v = 0;
    if (t < P && t >= off) v = sI[t - off];
    __syncthreads();
    if (t < P) sI[t] += v;
    __syncthreads();
  }
  if (t < P) {
    int g = max(giL[t], 10);
    out_grid[b * P + t] = (float)g;
    grid_i[b * P + t] = g;
    ends_i[b * P + t] = sI[t];
  }
}

// ---------------- K4: fused multi-scale conv via MFMA -> bf16 feats ----------------
template <int KS, int FB, int SBASE>
__device__ __forceinline__ void scale_mfma(const unsigned short* __restrict__ xs,
                                           const unsigned short* __restrict__ pw,
                                           const float* __restrict__ Aff,
                                           const float* __restrict__ Bff,
                                           unsigned short* __restrict__ feats,
                                           int b, int t0, int wt0, int lane) {
  constexpr int PAD = (KS - 1) / 2;
  const int n = lane & 15, q = lane >> 4;
  f32x4 acc[3][4];
  #pragma unroll
  for (int ot = 0; ot < 3; ++ot)
    #pragma unroll
    for (int ti = 0; ti < 4; ++ti)
      acc[ot][ti] = (f32x4){0.f, 0.f, 0.f, 0.f};

  const unsigned short* pws = pw + (size_t)FB * 512 + lane * 8;
  for (int k = 0; k < KS; ++k) {
    bf16x8 A0 = *(const bf16x8*)(pws + (size_t)(k * 3 + 0) * 512);
    bf16x8 A1 = *(const bf16x8*)(pws + (size_t)(k * 3 + 1) * 512);
    bf16x8 A2 = *(const bf16x8*)(pws + (size_t)(k * 3 + 2) * 512);
    int rbase = 24 - PAD + k + wt0 + n;
    #pragma unroll
    for (int ti = 0; ti < 4; ++ti) {
      bf16x8 Bf = *(const bf16x8*)(xs + (rbase + ti * 16) * RSTRIDE + q * 8);
      acc[0][ti] = __builtin_amdgcn_mfma_f32_16x16x32_bf16(A0, Bf, acc[0][ti], 0, 0, 0);
      acc[1][ti] = __builtin_amdgcn_mfma_f32_16x16x32_bf16(A1, Bf, acc[1][ti], 0, 0, 0);
      acc[2][ti] = __builtin_amdgcn_mfma_f32_16x16x32_bf16(A2, Bf, acc[2][ti], 0, 0, 0);
    }
  }
  // epilogue: C row = q*4+r (output channel within tile), col = n (time)
  #pragma unroll
  for (int ot = 0; ot < 3; ++ot) {
    #pragma unroll
    for (int r = 0; r < 4; ++r) {
      int o = ot * 16 + q * 4 + r;
      if (o < OC) {
        float Av = Aff[SBASE + o], Bv = Bff[SBASE + o];
        size_t rowoff = (size_t)(b * FC + SBASE + o) * T;
        #pragma unroll
        for (int ti = 0; ti < 4; ++ti) {
          int tt = t0 + wt0 + ti * 16 + n;
          if (tt < T) {
            float y = fmaf(acc[ot][ti][r], Av, Bv);
            float e = y > 0.f ? y : expm1f(y);
            feats[rowoff + tt] = f2bf(e);
          }
        }
      }
    }
  }
}

__global__ __launch_bounds__(256) void conv_mfma(const float* __restrict__ x,
                                                 const unsigned short* __restrict__ pw,
                                                 const float* __restrict__ Aff,
                                                 const float* __restrict__ Bff,
                                                 unsigned short* __restrict__ feats) {
  __shared__ unsigned short xs[ROWS * RSTRIDE];  // 24320 B, [t][h] bf16
  int b = blockIdx.y, t0 = blockIdx.x * 256;
  for (int idx = threadIdx.x; idx < CIN * ROWS; idx += 256) {
    int h = idx / ROWS, tl = idx - h * ROWS;
    int gt = t0 - 24 + tl;
    float v = (gt >= 0 && gt < T) ? x[(size_t)(b * CIN + h) * T + gt] : 0.f;
    xs[tl * RSTRIDE + h] = f2bf(v);
  }
  for (int idx = threadIdx.x; idx < 10 * ROWS; idx += 256) {
    int c = idx / ROWS, tl = idx - c * ROWS;
    xs[tl * RSTRIDE + 22 + c] = 0;
  }
  __syncthreads();
  int wv = threadIdx.x >> 6, lane = threadIdx.x & 63;
  int wt0 = wv * 64;
  scale_mfma<9, 0, 0>(xs, pw, Aff, Bff, feats, b, t0, wt0, lane);
  scale_mfma<25, 27, 40>(xs, pw, Aff, Bff, feats, b, t0, wt0, lane);
  scale_mfma<49, 102, 80>(xs, pw, Aff, Bff, feats, b, t0, wt0, lane);
}

// ---------------- K5: ragged avg+max pool + projection ----------------
__global__ __launch_bounds__(128) void pool_proj(const unsigned short* __restrict__ feats,
                                                 const int* __restrict__ ends_i,
                                                 const int* __restrict__ grid_i,
                                                 const float* __restrict__ proj_w,
                                                 const float* __restrict__ proj_b,
                                                 float* __restrict__ out_emb) {
  int bp = blockIdx.x;
  int b = bp / P;
  int end = ends_i[bp];
  int gr = grid_i[bp];
  int start = end - gr;
  __shared__ float pooled[FC];
  bool valid = (end <= T);
  int wv = threadIdx.x >> 6, lane = threadIdx.x & 63;
  if (valid) {
    for (int ch = wv; ch < FC; ch += 2) {
      const unsigned short* row = feats + (size_t)(b * FC + ch) * T;
      float s = 0.f, mx = -INFINITY;
      for (int tt = start + lane; tt < end; tt += 64) {
        float v = bf2f(row[tt]);
        s += v;
        mx = fmaxf(mx, v);
      }
      #pragma unroll
      for (int off = 1; off < 64; off <<= 1) {
        s += __shfl_xor(s, off);
        mx = fmaxf(mx, __shfl_xor(mx, off));
      }
      if (lane == 0) pooled[ch] = s / (float)gr + mx;
    }
  } else {
    for (int ch = threadIdx.x; ch < FC; ch += 128) pooled[ch] = 0.f;
  }
  __syncthreads();
  int o = threadIdx.x;
  if (o < EMB) {
    float e = proj_b[o];
    for (int c = 0; c < FC; ++c) e = fmaf(proj_w[o * FC + c], pooled[c], e);
    out_emb[(size_t)bp * EMB + o] = e;
  }
}

extern "C" void kernel_launch(void* const* d_in, const int* in_sizes, int n_in,
                              void* d_out, int out_size, void* d_ws, size_t ws_size,
                              hipStream_t stream) {
  const float* x = (const float*)d_in[0];
  const float* aw1 = (const float*)d_in[25];
  const float* ab1 = (const float*)d_in[26];
  const float* ag  = (const float*)d_in[27];
  const float* abt = (const float*)d_in[28];
  const float* am  = (const float*)d_in[29];
  const float* av  = (const float*)d_in[30];
  const float* aw2 = (const float*)d_in[31];
  const float* ab2 = (const float*)d_in[32];
  const float* proj_w = (const float*)d_in[33];
  const float* proj_b = (const float*)d_in[34];

  float* wsf = (float*)d_ws;
  float* W    = wsf;                 // 73040
  float* A    = wsf + 73040;         // 120
  float* Bc   = wsf + 73160;         // 120
  float* tcs  = wsf + 73280;         // 1408
  float* tsn  = wsf + 74688;         // 1408
  float* comb = wsf + 76096;         // 140800
  int* ends_i = (int*)(wsf + 216896);       // 3200
  int* grid_i = (int*)(wsf + 220096);       // 3200
  unsigned short* pw = (unsigned short*)(wsf + 223296);     // 127488 ushorts (249 frags x 512)
  unsigned short* feats = (unsigned short*)(wsf + 287040);  // 19.2M ushorts (38.4 MB)

  float* out      = (float*)d_out;
  float* out_emb  = out;             // 204800
  float* out_grid = out + 204800;    // 3200
  float* out_acti = out + 208000;    // 3200

  const int kss[3]   = {9, 25, 49};
  const int wbase[3] = {0, 7920, 29920};
  const int fbase[3] = {0, 27, 102};
  for (int s = 0; s < 3; ++s) {
    const float* w1 = (const float*)d_in[1 + 8 * s];
    const float* b1 = (const float*)d_in[2 + 8 * s];
    const float* w2 = (const float*)d_in[3 + 8 * s];
    const float* b2 = (const float*)d_in[4 + 8 * s];
    const float* g  = (const float*)d_in[5 + 8 * s];
    const float* bt = (const float*)d_in[6 + 8 * s];
    const float* m  = (const float*)d_in[7 + 8 * s];
    const float* v  = (const float*)d_in[8 + 8 * s];
    int n = OC * CIN * kss[s] + OC;
    prep_scale<<<(n + 255) / 256, 256, 0, stream>>>(w1, b1, w2, b2, g, bt, m, v,
                                                    kss[s], wbase[s], 40 * s, W, A, Bc);
  }
  for (int s = 0; s < 3; ++s) {
    int n = kss[s] * 3 * 512;
    pack_w<<<(n + 255) / 256, 256, 0, stream>>>(W, pw, kss[s], wbase[s], fbase[s]);
  }
  twiddles<<<(NBIN * 128 + 255) / 256, 256, 0, stream>>>(tcs, tsn);
  stft_comb<<<(B * CIN * NFR) / 256, 256, 0, stream>>>(x, tcs, tsn, comb);
  act_grid<<<B, 256, 0, stream>>>(comb, aw1, ab1, ag, abt, am, av, aw2, ab2,
                                  out_grid, out_acti, ends_i, grid_i);
  conv_mfma<<<dim3(20, B), 256, 0, stream>>>(x, pw, A, Bc, feats);
  pool_proj<<<B * P, 128, 0, stream>>>(feats, ends_i, grid_i, proj_w, proj_b, out_emb);
}

// Round 3
// 521.436 us; speedup vs baseline: 2.8424x; 1.4491x over previous
//
#include <hip/hip_runtime.h>
#include <math.h>

#define B 32
#define CIN 22
#define T 5000
#define EMB 64
#define P 100
#define HOP 25
#define OC 40
#define FC 120
#define NBIN 11   // rfft bins 5..15
#define NFR 200

#define ROWS 304      // 256-t chunk + 24 halo each side
#define RSTRIDE 40    // ushorts per xs row (80 B = 20 dwords -> bank-balanced)

typedef unsigned short ushort_t;
typedef __attribute__((ext_vector_type(8))) short bf16x8;
typedef __attribute__((ext_vector_type(4))) float f32x4;
struct __align__(8) US4 { unsigned short a, b, c, d; };

__device__ __forceinline__ unsigned short f2bf(float f) {
  unsigned u = __float_as_uint(f);
  unsigned r = (u + 0x7FFFu + ((u >> 16) & 1u)) >> 16;
  return (unsigned short)r;
}
__device__ __forceinline__ float bf2f(unsigned short u) {
  return __uint_as_float(((unsigned)u) << 16);
}

// ---------------- K1a: fuse conv1+conv2 weights per scale ----------------
__global__ void prep_scale(const float* __restrict__ w1, const float* __restrict__ b1,
                           const float* __restrict__ w2, const float* __restrict__ b2,
                           const float* __restrict__ g,  const float* __restrict__ bt,
                           const float* __restrict__ m,  const float* __restrict__ v,
                           int ks, int wbase, int abase,
                           float* __restrict__ W, float* __restrict__ A, float* __restrict__ Bc) {
  int nW = OC * CIN * ks;
  int id = blockIdx.x * 256 + threadIdx.x;
  if (id < nW) {
    int o = id / (CIN * ks);
    int rem = id - o * (CIN * ks);
    int h = rem / ks;
    int k = rem - h * ks;
    float s = 0.f;
    for (int i = 0; i < OC; ++i)
      s = fmaf(w2[(o * OC + i) * CIN + h], w1[i * ks + k], s);
    W[wbase + id] = s;
  } else if (id < nW + OC) {
    int o = id - nW;
    float sc = g[o] / sqrtf(v[o] + 1e-5f);
    float cc = b2[o];
    for (int i = 0; i < OC; ++i) {
      float sh = 0.f;
      for (int h = 0; h < CIN; ++h) sh += w2[(o * OC + i) * CIN + h];
      cc = fmaf(b1[i], sh, cc);
    }
    A[abase + o] = sc;
    Bc[abase + o] = cc * sc + (bt[o] - m[o] * sc);
  }
}

// ---------------- K1b: pack fused weights into MFMA A-fragment order ----------------
__global__ void pack_w(const float* __restrict__ W, unsigned short* __restrict__ pw,
                       int KS, int wbase, int fragbase) {
  int id = blockIdx.x * 256 + threadIdx.x;
  if (id >= KS * 3 * 512) return;
  int fi = id >> 9;
  int rem = id & 511;
  int lane = rem >> 3, j = rem & 7;
  int k = fi / 3, ot = fi - k * 3;
  int m = lane & 15, h = ((lane >> 4) << 3) + j;
  int o = ot * 16 + m;
  float v = (h < CIN && o < OC) ? W[wbase + (o * CIN + h) * KS + k] : 0.f;
  pw[(size_t)(fragbase + fi) * 512 + rem] = f2bf(v);
}

// ---------------- K1c: windowed DFT twiddles for bins 5..15 ----------------
__global__ void twiddles(float* __restrict__ tcos, float* __restrict__ tsin) {
  int id = blockIdx.x * 256 + threadIdx.x;
  if (id >= NBIN * 128) return;
  int k = id / 128 + 5, n = id - (id / 128) * 128;
  const double PI = 3.14159265358979323846;
  double ang = -2.0 * PI * (double)(k * n) / 128.0;
  double win = 0.5 * (1.0 - cos(2.0 * PI * (double)n / 128.0));
  tcos[id] = (float)(cos(ang) * win);
  tsin[id] = (float)(sin(ang) * win);
}

// ---------------- K2: STFT power -> comb ----------------
__global__ __launch_bounds__(256) void stft_comb(const float* __restrict__ x,
                                                 const float* __restrict__ tcg,
                                                 const float* __restrict__ tsg,
                                                 float* __restrict__ comb) {
  __shared__ float tc[NBIN * 128];
  __shared__ float ts[NBIN * 128];
  for (int i = threadIdx.x; i < NBIN * 128; i += 256) { tc[i] = tcg[i]; ts[i] = tsg[i]; }
  __syncthreads();
  int id = blockIdx.x * 256 + threadIdx.x;
  if (id >= B * CIN * NFR) return;
  int fr = id % NFR;
  int bc = id / NFR;
  const float* xr = x + (size_t)bc * T;
  float cr[NBIN], ci[NBIN];
  #pragma unroll
  for (int k = 0; k < NBIN; ++k) { cr[k] = 0.f; ci[k] = 0.f; }
  int base = fr * HOP - 64;
  for (int n = 0; n < 128; ++n) {
    int mm = base + n;
    mm = (mm < 0) ? -mm : mm;
    mm = (mm >= T) ? (2 * T - 2 - mm) : mm;
    float xv = xr[mm];
    #pragma unroll
    for (int k = 0; k < NBIN; ++k) {
      cr[k] = fmaf(xv, tc[k * 128 + n], cr[k]);
      ci[k] = fmaf(xv, ts[k * 128 + n], ci[k]);
    }
  }
  float p[NBIN];
  #pragma unroll
  for (int k = 0; k < NBIN; ++k) p[k] = cr[k] * cr[k] + ci[k] * ci[k];
  float beta = 0.f;
  #pragma unroll
  for (int k = 2; k < NBIN; ++k) beta += p[k];
  comb[id] = 0.5f * (p[0] + p[1]) + beta * (1.f / 9.f);
}

// ---------------- K3: activity conv + sigmoid + interp + adaptive grid ----------------
__device__ __forceinline__ float wave_sum_f(float v) {
  #pragma unroll
  for (int off = 1; off < 64; off <<= 1) v += __shfl_xor(v, off);
  return v;
}
__device__ __forceinline__ int wave_sum_i(int v) {
  #pragma unroll
  for (int off = 1; off < 64; off <<= 1) v += __shfl_xor(v, off);
  return v;
}

__global__ __launch_bounds__(256) void act_grid(const float* __restrict__ comb,
    const float* __restrict__ aw1, const float* __restrict__ ab1,
    const float* __restrict__ ag,  const float* __restrict__ abt,
    const float* __restrict__ am,  const float* __restrict__ av,
    const float* __restrict__ aw2, const float* __restrict__ ab2,
    float* __restrict__ out_grid, float* __restrict__ out_acti,
    int* __restrict__ ends_i, int* __restrict__ grid_i) {
  int b = blockIdx.x;
  __shared__ float cl[CIN * NFR];
  __shared__ float actL[NFR];
  __shared__ float aiL[P];
  __shared__ float fL[P];
  __shared__ int   giL[P];
  __shared__ int   sI[P];
  __shared__ float red[1];
  for (int i = threadIdx.x; i < CIN * NFR; i += 256) cl[i] = comb[b * CIN * NFR + i];
  __syncthreads();
  int t = threadIdx.x;
  if (t < NFR) {
    float z = ab2[0];
    for (int o = 0; o < 11; ++o) {
      float s = ab1[o];
      for (int i = 0; i < CIN; ++i) {
        const float* wr = aw1 + o * 66 + i * 3;
        const float* crow = cl + i * NFR;
        if (t > 0)       s = fmaf(wr[0], crow[t - 1], s);
        s = fmaf(wr[1], crow[t], s);
        if (t < NFR - 1) s = fmaf(wr[2], crow[t + 1], s);
      }
      float rs = 1.0f / sqrtf(av[o] + 1e-5f);
      float y = (s - am[o]) * rs * ag[o] + abt[o];
      y = fmaxf(y, 0.f);
      z = fmaf(aw2[o], y, z);
    }
    actL[t] = 1.f / (1.f + expf(-z));
  }
  __syncthreads();
  if (t < P) {
    float ai = 0.5f * (actL[2 * t] + actL[2 * t + 1]);
    aiL[t] = ai;
    out_acti[b * P + t] = ai;
    fL[t] = 1.f / (ai + 1e-6f);
  }
  __syncthreads();
  if (t < 64) {
    float v = fL[t] + ((t + 64 < P) ? fL[t + 64] : 0.f);
    v = wave_sum_f(v);
    if (t == 0) red[0] = v;
  }
  __syncthreads();
  float sw = red[0];
  if (t < P) {
    float gg = (fL[t] / sw) * 5000.f;
    gg = fminf(fmaxf(gg, 10.f), 100.f);
    fL[t] = gg;
  }
  __syncthreads();
  if (t < 64) {
    float v = fL[t] + ((t + 64 < P) ? fL[t + 64] : 0.f);
    v = wave_sum_f(v);
    if (t == 0) red[0] = v;
  }
  __syncthreads();
  float r = 5000.f / red[0];
  if (t < P) giL[t] = (int)rintf(fL[t] * r);
  __syncthreads();
  if (t < 64) {
    int v = giL[t] + ((t + 64 < P) ? giL[t + 64] : 0);
    v = wave_sum_i(v);
    if (t == 0) red[0] = __int_as_float(v);
  }
  __syncthreads();
  if (t == P - 1) giL[P - 1] += 5000 - __float_as_int(red[0]);
  __syncthreads();
  if (t < P) giL[t] = min(max(giL[t], 10), 100);
  __syncthreads();
  if (t < 64) {
    int v = giL[t] + ((t + 64 < P) ? giL[t + 64] : 0);
    v = wave_sum_i(v);
    if (t == 0) red[0] = __int_as_float(v);
  }
  __syncthreads();
  if (t == P - 1) giL[P - 1] += 5000 - __float_as_int(red[0]);
  __syncthreads();
  if (t < P) sI[t] = max(giL[t], 10);
  __syncthreads();
  #pragma unroll
  for (int off = 1; off < P; off <<= 1) {
    int v = 0;
    if (t < P && t >= off) v = sI[t - off];
    __syncthreads();
    if (t < P) sI[t] += v;
    __syncthreads();
  }
  if (t < P) {
    int g = max(giL[t], 10);
    out_grid[b * P + t] = (float)g;
    grid_i[b * P + t] = g;
    ends_i[b * P + t] = sI[t];
  }
}

// ---------------- K4: fused multi-scale conv via MFMA -> bf16 feats [b][t][ch] ----------------
template <int KS, int FB, int SBASE>
__device__ __forceinline__ void scale_mfma(const unsigned short* __restrict__ xs,
                                           const unsigned short* __restrict__ pw,
                                           const float* __restrict__ Aff,
                                           const float* __restrict__ Bff,
                                           unsigned short* __restrict__ feats,
                                           int b, int t0, int wt0, int lane) {
  constexpr int PAD = (KS - 1) / 2;
  const int n = lane & 15, q = lane >> 4;
  f32x4 acc[3][4];
  #pragma unroll
  for (int ot = 0; ot < 3; ++ot)
    #pragma unroll
    for (int ti = 0; ti < 4; ++ti)
      acc[ot][ti] = (f32x4){0.f, 0.f, 0.f, 0.f};

  const unsigned short* pws = pw + (size_t)FB * 512 + lane * 8;
  for (int k = 0; k < KS; ++k) {
    bf16x8 A0 = *(const bf16x8*)(pws + (size_t)(k * 3 + 0) * 512);
    bf16x8 A1 = *(const bf16x8*)(pws + (size_t)(k * 3 + 1) * 512);
    bf16x8 A2 = *(const bf16x8*)(pws + (size_t)(k * 3 + 2) * 512);
    int rbase = 24 - PAD + k + wt0 + n;
    #pragma unroll
    for (int ti = 0; ti < 4; ++ti) {
      bf16x8 Bf = *(const bf16x8*)(xs + (rbase + ti * 16) * RSTRIDE + q * 8);
      acc[0][ti] = __builtin_amdgcn_mfma_f32_16x16x32_bf16(A0, Bf, acc[0][ti], 0, 0, 0);
      acc[1][ti] = __builtin_amdgcn_mfma_f32_16x16x32_bf16(A1, Bf, acc[1][ti], 0, 0, 0);
      acc[2][ti] = __builtin_amdgcn_mfma_f32_16x16x32_bf16(A2, Bf, acc[2][ti], 0, 0, 0);
    }
  }
  // epilogue: lane holds channels o = ot*16 + q*4 + r (r=0..3, consecutive) at time tt
  // feats layout: [b][t][ch] -> one packed 8B store per (ot, ti)
  #pragma unroll
  for (int ot = 0; ot < 3; ++ot) {
    int obase = ot * 16 + q * 4;   // 0..60, +3 fits since OC=40 tiles: ot=2 -> 32+q*4 <= 44? (q<=3 -> 44) guard below
    #pragma unroll
    for (int ti = 0; ti < 4; ++ti) {
      int tt = t0 + wt0 + ti * 16 + n;
      if (tt < T && obase + 3 < OC + 8) { // obase can reach 44; only obase<40 valid
        if (obase < OC) {
          float e4[4];
          #pragma unroll
          for (int r = 0; r < 4; ++r) {
            float Av = Aff[SBASE + obase + r], Bv = Bff[SBASE + obase + r];
            float y = fmaf(acc[ot][ti][r], Av, Bv);
            e4[r] = y > 0.f ? y : expm1f(y);
          }
          US4 pk; pk.a = f2bf(e4[0]); pk.b = f2bf(e4[1]); pk.c = f2bf(e4[2]); pk.d = f2bf(e4[3]);
          *reinterpret_cast<US4*>(feats + (size_t)(b * T + tt) * FC + SBASE + obase) = pk;
        }
      }
    }
  }
}

__global__ __launch_bounds__(256) void conv_mfma(const float* __restrict__ x,
                                                 const unsigned short* __restrict__ pw,
                                                 const float* __restrict__ Aff,
                                                 const float* __restrict__ Bff,
                                                 unsigned short* __restrict__ feats) {
  __shared__ unsigned short xs[ROWS * RSTRIDE];  // 24320 B, [t][h] bf16
  int b = blockIdx.y, t0 = blockIdx.x * 256;
  for (int idx = threadIdx.x; idx < CIN * ROWS; idx += 256) {
    int h = idx / ROWS, tl = idx - h * ROWS;
    int gt = t0 - 24 + tl;
    float v = (gt >= 0 && gt < T) ? x[(size_t)(b * CIN + h) * T + gt] : 0.f;
    xs[tl * RSTRIDE + h] = f2bf(v);
  }
  for (int idx = threadIdx.x; idx < 10 * ROWS; idx += 256) {
    int c = idx / ROWS, tl = idx - c * ROWS;
    xs[tl * RSTRIDE + 22 + c] = 0;
  }
  __syncthreads();
  int wv = threadIdx.x >> 6, lane = threadIdx.x & 63;
  int wt0 = wv * 64;
  scale_mfma<9, 0, 0>(xs, pw, Aff, Bff, feats, b, t0, wt0, lane);
  scale_mfma<25, 27, 40>(xs, pw, Aff, Bff, feats, b, t0, wt0, lane);
  scale_mfma<49, 102, 80>(xs, pw, Aff, Bff, feats, b, t0, wt0, lane);
}

// ---------------- K5: ragged avg+max pool + projection (lane = channel) ----------------
__global__ __launch_bounds__(128) void pool_proj(const unsigned short* __restrict__ feats,
                                                 const int* __restrict__ ends_i,
                                                 const int* __restrict__ grid_i,
                                                 const float* __restrict__ proj_w,
                                                 const float* __restrict__ proj_b,
                                                 float* __restrict__ out_emb) {
  int bp = blockIdx.x;
  int b = bp / P;
  int end = ends_i[bp];
  int gr = grid_i[bp];
  int start = end - gr;
  __shared__ float pooled[FC];
  int tid = threadIdx.x;
  bool valid = (end <= T);
  if (tid < FC) {
    if (valid) {
      const unsigned short* base = feats + (size_t)(b * T + start) * FC + tid;
      float s = 0.f, mx = -INFINITY;
      int i = 0;
      for (; i + 4 <= gr; i += 4) {
        float v0 = bf2f(base[(size_t)(i + 0) * FC]);
        float v1 = bf2f(base[(size_t)(i + 1) * FC]);
        float v2 = bf2f(base[(size_t)(i + 2) * FC]);
        float v3 = bf2f(base[(size_t)(i + 3) * FC]);
        s += (v0 + v1) + (v2 + v3);
        mx = fmaxf(mx, fmaxf(fmaxf(v0, v1), fmaxf(v2, v3)));
      }
      for (; i < gr; ++i) {
        float v = bf2f(base[(size_t)i * FC]);
        s += v;
        mx = fmaxf(mx, v);
      }
      pooled[tid] = s / (float)gr + mx;
    } else {
      pooled[tid] = 0.f;
    }
  }
  __syncthreads();
  int o = tid;
  if (o < EMB) {
    float e = proj_b[o];
    const float* wr = proj_w + o * FC;
    #pragma unroll 8
    for (int c = 0; c < FC; ++c) e = fmaf(wr[c], pooled[c], e);
    out_emb[(size_t)bp * EMB + o] = e;
  }
}

extern "C" void kernel_launch(void* const* d_in, const int* in_sizes, int n_in,
                              void* d_out, int out_size, void* d_ws, size_t ws_size,
                              hipStream_t stream) {
  const float* x = (const float*)d_in[0];
  const float* aw1 = (const float*)d_in[25];
  const float* ab1 = (const float*)d_in[26];
  const float* ag  = (const float*)d_in[27];
  const float* abt = (const float*)d_in[28];
  const float* am  = (const float*)d_in[29];
  const float* av  = (const float*)d_in[30];
  const float* aw2 = (const float*)d_in[31];
  const float* ab2 = (const float*)d_in[32];
  const float* proj_w = (const float*)d_in[33];
  const float* proj_b = (const float*)d_in[34];

  float* wsf = (float*)d_ws;
  float* W    = wsf;                 // 73040
  float* A    = wsf + 73040;         // 120
  float* Bc   = wsf + 73160;         // 120
  float* tcs  = wsf + 73280;         // 1408
  float* tsn  = wsf + 74688;         // 1408
  float* comb = wsf + 76096;         // 140800
  int* ends_i = (int*)(wsf + 216896);       // 3200
  int* grid_i = (int*)(wsf + 220096);       // 3200
  unsigned short* pw = (unsigned short*)(wsf + 223296);     // 127488 ushorts
  unsigned short* feats = (unsigned short*)(wsf + 287040);  // 19.2M ushorts (38.4 MB)

  float* out      = (float*)d_out;
  float* out_emb  = out;             // 204800
  float* out_grid = out + 204800;    // 3200
  float* out_acti = out + 208000;    // 3200

  const int kss[3]   = {9, 25, 49};
  const int wbase[3] = {0, 7920, 29920};
  const int fbase[3] = {0, 27, 102};
  for (int s = 0; s < 3; ++s) {
    const float* w1 = (const float*)d_in[1 + 8 * s];
    const float* b1 = (const float*)d_in[2 + 8 * s];
    const float* w2 = (const float*)d_in[3 + 8 * s];
    const float* b2 = (const float*)d_in[4 + 8 * s];
    const float* g  = (const float*)d_in[5 + 8 * s];
    const float* bt = (const float*)d_in[6 + 8 * s];
    const float* m  = (const float*)d_in[7 + 8 * s];
    const float* v  = (const float*)d_in[8 + 8 * s];
    int n = OC * CIN * kss[s] + OC;
    prep_scale<<<(n + 255) / 256, 256, 0, stream>>>(w1, b1, w2, b2, g, bt, m, v,
                                                    kss[s], wbase[s], 40 * s, W, A, Bc);
  }
  for (int s = 0; s < 3; ++s) {
    int n = kss[s] * 3 * 512;
    pack_w<<<(n + 255) / 256, 256, 0, stream>>>(W, pw, kss[s], wbase[s], fbase[s]);
  }
  twiddles<<<(NBIN * 128 + 255) / 256, 256, 0, stream>>>(tcs, tsn);
  stft_comb<<<(B * CIN * NFR) / 256, 256, 0, stream>>>(x, tcs, tsn, comb);
  act_grid<<<B, 256, 0, stream>>>(comb, aw1, ab1, ag, abt, am, av, aw2, ab2,
                                  out_grid, out_acti, ends_i, grid_i);
  conv_mfma<<<dim3(20, B), 256, 0, stream>>>(x, pw, A, Bc, feats);
  pool_proj<<<B * P, 128, 0, stream>>>(feats, ends_i, grid_i, proj_w, proj_b, out_emb);
}

// Round 5
// 397.765 us; speedup vs baseline: 3.7262x; 1.3109x over previous
//
#include <hip/hip_runtime.h>
#include <math.h>

#define B 32
#define CIN 22
#define T 5000
#define EMB 64
#define P 100
#define HOP 25
#define OC 40
#define FC 120
#define NBIN 11   // rfft bins 5..15
#define NFR 200

#define ROWS 304      // 256-t chunk + 24 halo each side
#define RSTRIDE 40    // ushorts per xs row (80 B = 20 dwords)

typedef unsigned short ushort_t;
typedef __attribute__((ext_vector_type(8))) short bf16x8;
typedef __attribute__((ext_vector_type(4))) float f32x4;
struct __align__(8) US4 { unsigned short a, b, c, d; };

__device__ __forceinline__ unsigned short f2bf(float f) {
  unsigned u = __float_as_uint(f);
  unsigned r = (u + 0x7FFFu + ((u >> 16) & 1u)) >> 16;
  return (unsigned short)r;
}
__device__ __forceinline__ float bf2f(unsigned short u) {
  return __uint_as_float(((unsigned)u) << 16);
}
__device__ __forceinline__ float fast_elu(float y) {
  // ELU: y>0 ? y : exp(y)-1, exp via native exp2
  return y > 0.f ? y : (__builtin_amdgcn_exp2f(y * 1.44269504088896340736f) - 1.0f);
}

// ---------------- K1: merged setup (fused-weight pack + twiddles + affine) ----------------
struct SetupArgs {
  const float* w1[3]; const float* b1[3]; const float* w2[3]; const float* b2[3];
  const float* g[3];  const float* bt[3]; const float* m[3];  const float* v[3];
  unsigned short* pw;
  float* A; float* Bc; float* tcs; float* tsn;
};

__global__ __launch_bounds__(256) void setup_all(SetupArgs args) {
  if (blockIdx.x < 498) {
    // pack fused conv weights directly into MFMA A-fragment order
    int id = blockIdx.x * 256 + threadIdx.x;
    int s, KS, fbase, idl;
    if (id < 13824)       { s = 0; KS = 9;  fbase = 0;   idl = id; }
    else if (id < 52224)  { s = 1; KS = 25; fbase = 27;  idl = id - 13824; }
    else                  { s = 2; KS = 49; fbase = 102; idl = id - 52224; }
    int fi = idl >> 9, rem = idl & 511;
    int lane = rem >> 3, j = rem & 7;
    int k = fi / 3, ot = fi - k * 3;
    int m = lane & 15, h = ((lane >> 4) << 3) + j;
    int o = ot * 16 + m;
    float val = 0.f;
    if (h < CIN && o < OC) {
      const float* w1 = args.w1[s];
      const float* w2 = args.w2[s];
      for (int i = 0; i < OC; ++i)
        val = fmaf(w2[(o * OC + i) * CIN + h], w1[i * KS + k], val);
    }
    args.pw[(size_t)(fbase + fi) * 512 + rem] = f2bf(val);
  } else if (blockIdx.x < 504) {
    int id = (blockIdx.x - 498) * 256 + threadIdx.x;
    if (id < NBIN * 128) {
      int k = id / 128 + 5, n = id - (id / 128) * 128;
      const double PI = 3.14159265358979323846;
      double ang = -2.0 * PI * (double)(k * n) / 128.0;
      double win = 0.5 * (1.0 - cos(2.0 * PI * (double)n / 128.0));
      args.tcs[id] = (float)(cos(ang) * win);
      args.tsn[id] = (float)(sin(ang) * win);
    }
  } else {
    int id = threadIdx.x;
    if (id < 120) {
      int s = id / 40, o = id - s * 40;
      const float* w2 = args.w2[s];
      float sc = args.g[s][o] / sqrtf(args.v[s][o] + 1e-5f);
      float cc = args.b2[s][o];
      for (int i = 0; i < OC; ++i) {
        float sh = 0.f;
        for (int h = 0; h < CIN; ++h) sh += w2[(o * OC + i) * CIN + h];
        cc = fmaf(args.b1[s][i], sh, cc);
      }
      args.A[id] = sc;
      args.Bc[id] = cc * sc + (args.bt[s][o] - args.m[s][o] * sc);
    }
  }
}

// ---------------- K2: STFT power -> comb ----------------
__global__ __launch_bounds__(256) void stft_comb(const float* __restrict__ x,
                                                 const float* __restrict__ tcg,
                                                 const float* __restrict__ tsg,
                                                 float* __restrict__ comb) {
  __shared__ float tc[NBIN * 128];
  __shared__ float ts[NBIN * 128];
  for (int i = threadIdx.x; i < NBIN * 128; i += 256) { tc[i] = tcg[i]; ts[i] = tsg[i]; }
  __syncthreads();
  int id = blockIdx.x * 256 + threadIdx.x;
  if (id >= B * CIN * NFR) return;
  int fr = id % NFR;
  int bc = id / NFR;
  const float* xr = x + (size_t)bc * T;
  float cr[NBIN], ci[NBIN];
  #pragma unroll
  for (int k = 0; k < NBIN; ++k) { cr[k] = 0.f; ci[k] = 0.f; }
  int base = fr * HOP - 64;
  for (int n = 0; n < 128; ++n) {
    int mm = base + n;
    mm = (mm < 0) ? -mm : mm;
    mm = (mm >= T) ? (2 * T - 2 - mm) : mm;
    float xv = xr[mm];
    #pragma unroll
    for (int k = 0; k < NBIN; ++k) {
      cr[k] = fmaf(xv, tc[k * 128 + n], cr[k]);
      ci[k] = fmaf(xv, ts[k * 128 + n], ci[k]);
    }
  }
  float p[NBIN];
  #pragma unroll
  for (int k = 0; k < NBIN; ++k) p[k] = cr[k] * cr[k] + ci[k] * ci[k];
  float beta = 0.f;
  #pragma unroll
  for (int k = 2; k < NBIN; ++k) beta += p[k];
  comb[id] = 0.5f * (p[0] + p[1]) + beta * (1.f / 9.f);
}

// ---------------- K3: activity conv + sigmoid + interp + adaptive grid ----------------
__device__ __forceinline__ float wave_sum_f(float v) {
  #pragma unroll
  for (int off = 1; off < 64; off <<= 1) v += __shfl_xor(v, off);
  return v;
}
__device__ __forceinline__ int wave_sum_i(int v) {
  #pragma unroll
  for (int off = 1; off < 64; off <<= 1) v += __shfl_xor(v, off);
  return v;
}

__global__ __launch_bounds__(256) void act_grid(const float* __restrict__ comb,
    const float* __restrict__ aw1, const float* __restrict__ ab1,
    const float* __restrict__ ag,  const float* __restrict__ abt,
    const float* __restrict__ am,  const float* __restrict__ av,
    const float* __restrict__ aw2, const float* __restrict__ ab2,
    float* __restrict__ out_grid, float* __restrict__ out_acti,
    int* __restrict__ ends_i, int* __restrict__ grid_i) {
  int b = blockIdx.x;
  __shared__ float cl[CIN * NFR];
  __shared__ float actL[NFR];
  __shared__ float aiL[P];
  __shared__ float fL[P];
  __shared__ int   giL[P];
  __shared__ int   sI[P];
  __shared__ float red[1];
  for (int i = threadIdx.x; i < CIN * NFR; i += 256) cl[i] = comb[b * CIN * NFR + i];
  __syncthreads();
  int t = threadIdx.x;
  if (t < NFR) {
    float z = ab2[0];
    for (int o = 0; o < 11; ++o) {
      float s = ab1[o];
      for (int i = 0; i < CIN; ++i) {
        const float* wr = aw1 + o * 66 + i * 3;
        const float* crow = cl + i * NFR;
        if (t > 0)       s = fmaf(wr[0], crow[t - 1], s);
        s = fmaf(wr[1], crow[t], s);
        if (t < NFR - 1) s = fmaf(wr[2], crow[t + 1], s);
      }
      float rs = 1.0f / sqrtf(av[o] + 1e-5f);
      float y = (s - am[o]) * rs * ag[o] + abt[o];
      y = fmaxf(y, 0.f);
      z = fmaf(aw2[o], y, z);
    }
    actL[t] = 1.f / (1.f + expf(-z));
  }
  __syncthreads();
  if (t < P) {
    float ai = 0.5f * (actL[2 * t] + actL[2 * t + 1]);
    aiL[t] = ai;
    out_acti[b * P + t] = ai;
    fL[t] = 1.f / (ai + 1e-6f);
  }
  __syncthreads();
  if (t < 64) {
    float v = fL[t] + ((t + 64 < P) ? fL[t + 64] : 0.f);
    v = wave_sum_f(v);
    if (t == 0) red[0] = v;
  }
  __syncthreads();
  float sw = red[0];
  if (t < P) {
    float gg = (fL[t] / sw) * 5000.f;
    gg = fminf(fmaxf(gg, 10.f), 100.f);
    fL[t] = gg;
  }
  __syncthreads();
  if (t < 64) {
    float v = fL[t] + ((t + 64 < P) ? fL[t + 64] : 0.f);
    v = wave_sum_f(v);
    if (t == 0) red[0] = v;
  }
  __syncthreads();
  float r = 5000.f / red[0];
  if (t < P) giL[t] = (int)rintf(fL[t] * r);
  __syncthreads();
  if (t < 64) {
    int v = giL[t] + ((t + 64 < P) ? giL[t + 64] : 0);
    v = wave_sum_i(v);
    if (t == 0) red[0] = __int_as_float(v);
  }
  __syncthreads();
  if (t == P - 1) giL[P - 1] += 5000 - __float_as_int(red[0]);
  __syncthreads();
  if (t < P) giL[t] = min(max(giL[t], 10), 100);
  __syncthreads();
  if (t < 64) {
    int v = giL[t] + ((t + 64 < P) ? giL[t + 64] : 0);
    v = wave_sum_i(v);
    if (t == 0) red[0] = __int_as_float(v);
  }
  __syncthreads();
  if (t == P - 1) giL[P - 1] += 5000 - __float_as_int(red[0]);
  __syncthreads();
  if (t < P) sI[t] = max(giL[t], 10);
  __syncthreads();
  #pragma unroll
  for (int off = 1; off < P; off <<= 1) {
    int v = 0;
    if (t < P && t >= off) v = sI[t - off];
    __syncthreads();
    if (t < P) sI[t] += v;
    __syncthreads();
  }
  if (t < P) {
    int g = max(giL[t], 10);
    out_grid[b * P + t] = (float)g;
    grid_i[b * P + t] = g;
    ends_i[b * P + t] = sI[t];
  }
}

// ---------------- K4: fused multi-scale conv via MFMA, one scale per block ----------------
template <int KS, int FB, int SBASE>
__device__ __forceinline__ void scale_body(const unsigned short* __restrict__ xs,
                                           const unsigned short* __restrict__ pw,
                                           const float* __restrict__ Aff,
                                           const float* __restrict__ Bff,
                                           unsigned short* __restrict__ feats,
                                           int b, int t0, int wt0, int lane) {
  constexpr int PAD = (KS - 1) / 2;
  const int n = lane & 15, q = lane >> 4;
  f32x4 acc[3][4];
  #pragma unroll
  for (int ot = 0; ot < 3; ++ot)
    #pragma unroll
    for (int ti = 0; ti < 4; ++ti)
      acc[ot][ti] = (f32x4){0.f, 0.f, 0.f, 0.f};

  const unsigned short* pws = pw + (size_t)FB * 512 + lane * 8;
  #pragma unroll 1
  for (int k = 0; k < KS; ++k) {
    bf16x8 A0 = *(const bf16x8*)(pws + (size_t)(k * 3 + 0) * 512);
    bf16x8 A1 = *(const bf16x8*)(pws + (size_t)(k * 3 + 1) * 512);
    bf16x8 A2 = *(const bf16x8*)(pws + (size_t)(k * 3 + 2) * 512);
    int rbase = 24 - PAD + k + wt0 + n;
    #pragma unroll
    for (int ti = 0; ti < 4; ++ti) {
      bf16x8 Bf = *(const bf16x8*)(xs + (rbase + ti * 16) * RSTRIDE + q * 8);
      acc[0][ti] = __builtin_amdgcn_mfma_f32_16x16x32_bf16(A0, Bf, acc[0][ti], 0, 0, 0);
      acc[1][ti] = __builtin_amdgcn_mfma_f32_16x16x32_bf16(A1, Bf, acc[1][ti], 0, 0, 0);
      acc[2][ti] = __builtin_amdgcn_mfma_f32_16x16x32_bf16(A2, Bf, acc[2][ti], 0, 0, 0);
    }
  }
  #pragma unroll
  for (int ot = 0; ot < 3; ++ot) {
    int obase = ot * 16 + q * 4;
    if (obase < OC) {
      float Av0 = Aff[SBASE + obase + 0], Bv0 = Bff[SBASE + obase + 0];
      float Av1 = Aff[SBASE + obase + 1], Bv1 = Bff[SBASE + obase + 1];
      float Av2 = Aff[SBASE + obase + 2], Bv2 = Bff[SBASE + obase + 2];
      float Av3 = Aff[SBASE + obase + 3], Bv3 = Bff[SBASE + obase + 3];
      #pragma unroll
      for (int ti = 0; ti < 4; ++ti) {
        int tt = t0 + wt0 + ti * 16 + n;
        if (tt < T) {
          US4 pk;
          pk.a = f2bf(fast_elu(fmaf(acc[ot][ti][0], Av0, Bv0)));
          pk.b = f2bf(fast_elu(fmaf(acc[ot][ti][1], Av1, Bv1)));
          pk.c = f2bf(fast_elu(fmaf(acc[ot][ti][2], Av2, Bv2)));
          pk.d = f2bf(fast_elu(fmaf(acc[ot][ti][3], Av3, Bv3)));
          *reinterpret_cast<US4*>(feats + (size_t)(b * T + tt) * FC + SBASE + obase) = pk;
        }
      }
    }
  }
}

__global__ __launch_bounds__(256) void conv_mfma(const float* __restrict__ x,
                                                 const unsigned short* __restrict__ pw,
                                                 const float* __restrict__ Aff,
                                                 const float* __restrict__ Bff,
                                                 unsigned short* __restrict__ feats) {
  __shared__ unsigned short xs[ROWS * RSTRIDE];  // 24320 B, [t][h] bf16
  int b = blockIdx.y, t0 = blockIdx.x * 256;
  for (int idx = threadIdx.x; idx < CIN * ROWS; idx += 256) {
    int h = idx / ROWS, tl = idx - h * ROWS;
    int gt = t0 - 24 + tl;
    float v = (gt >= 0 && gt < T) ? x[(size_t)(b * CIN + h) * T + gt] : 0.f;
    xs[tl * RSTRIDE + h] = f2bf(v);
  }
  for (int idx = threadIdx.x; idx < 10 * ROWS; idx += 256) {
    int c = idx / ROWS, tl = idx - c * ROWS;
    xs[tl * RSTRIDE + 22 + c] = 0;
  }
  __syncthreads();
  int wv = threadIdx.x >> 6, lane = threadIdx.x & 63;
  int wt0 = wv * 64;
  if (blockIdx.z == 0)
    scale_body<9, 0, 0>(xs, pw, Aff, Bff, feats, b, t0, wt0, lane);
  else if (blockIdx.z == 1)
    scale_body<25, 27, 40>(xs, pw, Aff, Bff, feats, b, t0, wt0, lane);
  else
    scale_body<49, 102, 80>(xs, pw, Aff, Bff, feats, b, t0, wt0, lane);
}

// ---------------- K5: ragged avg+max pool + projection (lane = channel) ----------------
__global__ __launch_bounds__(128) void pool_proj(const unsigned short* __restrict__ feats,
                                                 const int* __restrict__ ends_i,
                                                 const int* __restrict__ grid_i,
                                                 const float* __restrict__ proj_w,
                                                 const float* __restrict__ proj_b,
                                                 float* __restrict__ out_emb) {
  int bp = blockIdx.x;
  int b = bp / P;
  int end = ends_i[bp];
  int gr = grid_i[bp];
  int start = end - gr;
  __shared__ float pooled[FC];
  int tid = threadIdx.x;
  bool valid = (end <= T);
  if (tid < FC) {
    if (valid) {
      const unsigned short* base = feats + (size_t)(b * T + start) * FC + tid;
      float s = 0.f, mx = -INFINITY;
      int i = 0;
      for (; i + 4 <= gr; i += 4) {
        float v0 = bf2f(base[(size_t)(i + 0) * FC]);
        float v1 = bf2f(base[(size_t)(i + 1) * FC]);
        float v2 = bf2f(base[(size_t)(i + 2) * FC]);
        float v3 = bf2f(base[(size_t)(i + 3) * FC]);
        s += (v0 + v1) + (v2 + v3);
        mx = fmaxf(mx, fmaxf(fmaxf(v0, v1), fmaxf(v2, v3)));
      }
      for (; i < gr; ++i) {
        float v = bf2f(base[(size_t)i * FC]);
        s += v;
        mx = fmaxf(mx, v);
      }
      pooled[tid] = s / (float)gr + mx;
    } else {
      pooled[tid] = 0.f;
    }
  }
  __syncthreads();
  int o = tid;
  if (o < EMB) {
    float e = proj_b[o];
    const float* wr = proj_w + o * FC;
    #pragma unroll 8
    for (int c = 0; c < FC; ++c) e = fmaf(wr[c], pooled[c], e);
    out_emb[(size_t)bp * EMB + o] = e;
  }
}

extern "C" void kernel_launch(void* const* d_in, const int* in_sizes, int n_in,
                              void* d_out, int out_size, void* d_ws, size_t ws_size,
                              hipStream_t stream) {
  const float* x = (const float*)d_in[0];
  const float* aw1 = (const float*)d_in[25];
  const float* ab1 = (const float*)d_in[26];
  const float* ag  = (const float*)d_in[27];
  const float* abt = (const float*)d_in[28];
  const float* am  = (const float*)d_in[29];
  const float* av  = (const float*)d_in[30];
  const float* aw2 = (const float*)d_in[31];
  const float* ab2 = (const float*)d_in[32];
  const float* proj_w = (const float*)d_in[33];
  const float* proj_b = (const float*)d_in[34];

  float* wsf = (float*)d_ws;
  float* A    = wsf;                 // 120
  float* Bc   = wsf + 120;           // 120
  float* tcs  = wsf + 240;           // 1408
  float* tsn  = wsf + 1648;          // 1408
  float* comb = wsf + 3056;          // 140800
  int* ends_i = (int*)(wsf + 143856);       // 3200
  int* grid_i = (int*)(wsf + 147056);       // 3200
  unsigned short* pw = (unsigned short*)(wsf + 150256);     // 127488 ushorts
  unsigned short* feats = (unsigned short*)(wsf + 214000);  // 19.2M ushorts (38.4 MB)

  float* out      = (float*)d_out;
  float* out_emb  = out;             // 204800
  float* out_grid = out + 204800;    // 3200
  float* out_acti = out + 208000;    // 3200

  SetupArgs sa;
  for (int s = 0; s < 3; ++s) {
    sa.w1[s] = (const float*)d_in[1 + 8 * s];
    sa.b1[s] = (const float*)d_in[2 + 8 * s];
    sa.w2[s] = (const float*)d_in[3 + 8 * s];
    sa.b2[s] = (const float*)d_in[4 + 8 * s];
    sa.g[s]  = (const float*)d_in[5 + 8 * s];
    sa.bt[s] = (const float*)d_in[6 + 8 * s];
    sa.m[s]  = (const float*)d_in[7 + 8 * s];
    sa.v[s]  = (const float*)d_in[8 + 8 * s];
  }
  sa.pw = pw; sa.A = A; sa.Bc = Bc; sa.tcs = tcs; sa.tsn = tsn;

  setup_all<<<505, 256, 0, stream>>>(sa);
  stft_comb<<<(B * CIN * NFR) / 256, 256, 0, stream>>>(x, tcs, tsn, comb);
  act_grid<<<B, 256, 0, stream>>>(comb, aw1, ab1, ag, abt, am, av, aw2, ab2,
                                  out_grid, out_acti, ends_i, grid_i);
  conv_mfma<<<dim3(20, B, 3), 256, 0, stream>>>(x, pw, A, Bc, feats);
  pool_proj<<<B * P, 128, 0, stream>>>(feats, ends_i, grid_i, proj_w, proj_b, out_emb);
}

// Round 6
// 363.039 us; speedup vs baseline: 4.0826x; 1.0957x over previous
//
#include <hip/hip_runtime.h>
#include <math.h>

#define B 32
#define CIN 22
#define T 5000
#define EMB 64
#define P 100
#define HOP 25
#define OC 40
#define FC 120
#define NBIN 11   // rfft bins 5..15
#define NFR 200

#define ROWS 304      // 256-t chunk + 24 halo each side
#define RSTRIDE 40    // ushorts per xs row (80 B = 20 dwords)

typedef unsigned short ushort_t;
typedef __attribute__((ext_vector_type(8))) short bf16x8;
typedef __attribute__((ext_vector_type(4))) float f32x4;
struct __align__(8) US4 { unsigned short a, b, c, d; };

__device__ __forceinline__ unsigned short f2bf(float f) {
  unsigned u = __float_as_uint(f);
  unsigned r = (u + 0x7FFFu + ((u >> 16) & 1u)) >> 16;
  return (unsigned short)r;
}
__device__ __forceinline__ float bf2f(unsigned short u) {
  return __uint_as_float(((unsigned)u) << 16);
}
__device__ __forceinline__ float fast_elu(float y) {
  return y > 0.f ? y : (__builtin_amdgcn_exp2f(y * 1.44269504088896340736f) - 1.0f);
}

// ---------------- K1: merged setup (fused-weight pack + twiddles + affine) ----------------
struct SetupArgs {
  const float* w1[3]; const float* b1[3]; const float* w2[3]; const float* b2[3];
  const float* g[3];  const float* bt[3]; const float* m[3];  const float* v[3];
  unsigned short* pw;
  float* A; float* Bc; float* tcs; float* tsn;
};

__global__ __launch_bounds__(256) void setup_all(SetupArgs args) {
  if (blockIdx.x < 498) {
    int id = blockIdx.x * 256 + threadIdx.x;
    int s, KS, fbase, idl;
    if (id < 13824)       { s = 0; KS = 9;  fbase = 0;   idl = id; }
    else if (id < 52224)  { s = 1; KS = 25; fbase = 27;  idl = id - 13824; }
    else                  { s = 2; KS = 49; fbase = 102; idl = id - 52224; }
    int fi = idl >> 9, rem = idl & 511;
    int lane = rem >> 3, j = rem & 7;
    int k = fi / 3, ot = fi - k * 3;
    int m = lane & 15, h = ((lane >> 4) << 3) + j;
    int o = ot * 16 + m;
    float val = 0.f;
    if (h < CIN && o < OC) {
      const float* w1 = args.w1[s];
      const float* w2 = args.w2[s];
      for (int i = 0; i < OC; ++i)
        val = fmaf(w2[(o * OC + i) * CIN + h], w1[i * KS + k], val);
    }
    args.pw[(size_t)(fbase + fi) * 512 + rem] = f2bf(val);
  } else if (blockIdx.x < 504) {
    int id = (blockIdx.x - 498) * 256 + threadIdx.x;
    if (id < NBIN * 128) {
      int k = id / 128 + 5, n = id - (id / 128) * 128;
      const double PI = 3.14159265358979323846;
      double ang = -2.0 * PI * (double)(k * n) / 128.0;
      double win = 0.5 * (1.0 - cos(2.0 * PI * (double)n / 128.0));
      args.tcs[id] = (float)(cos(ang) * win);
      args.tsn[id] = (float)(sin(ang) * win);
    }
  } else {
    int id = threadIdx.x;
    if (id < 120) {
      int s = id / 40, o = id - s * 40;
      const float* w2 = args.w2[s];
      float sc = args.g[s][o] / sqrtf(args.v[s][o] + 1e-5f);
      float cc = args.b2[s][o];
      for (int i = 0; i < OC; ++i) {
        float sh = 0.f;
        for (int h = 0; h < CIN; ++h) sh += w2[(o * OC + i) * CIN + h];
        cc = fmaf(args.b1[s][i], sh, cc);
      }
      args.A[id] = sc;
      args.Bc[id] = cc * sc + (args.bt[s][o] - args.m[s][o] * sc);
    }
  }
}

// ---------------- K2: STFT power -> comb ----------------
__global__ __launch_bounds__(256) void stft_comb(const float* __restrict__ x,
                                                 const float* __restrict__ tcg,
                                                 const float* __restrict__ tsg,
                                                 float* __restrict__ comb) {
  __shared__ float tc[NBIN * 128];
  __shared__ float ts[NBIN * 128];
  for (int i = threadIdx.x; i < NBIN * 128; i += 256) { tc[i] = tcg[i]; ts[i] = tsg[i]; }
  __syncthreads();
  int id = blockIdx.x * 256 + threadIdx.x;
  if (id >= B * CIN * NFR) return;
  int fr = id % NFR;
  int bc = id / NFR;
  const float* xr = x + (size_t)bc * T;
  float cr[NBIN], ci[NBIN];
  #pragma unroll
  for (int k = 0; k < NBIN; ++k) { cr[k] = 0.f; ci[k] = 0.f; }
  int base = fr * HOP - 64;
  for (int n = 0; n < 128; ++n) {
    int mm = base + n;
    mm = (mm < 0) ? -mm : mm;
    mm = (mm >= T) ? (2 * T - 2 - mm) : mm;
    float xv = xr[mm];
    #pragma unroll
    for (int k = 0; k < NBIN; ++k) {
      cr[k] = fmaf(xv, tc[k * 128 + n], cr[k]);
      ci[k] = fmaf(xv, ts[k * 128 + n], ci[k]);
    }
  }
  float p[NBIN];
  #pragma unroll
  for (int k = 0; k < NBIN; ++k) p[k] = cr[k] * cr[k] + ci[k] * ci[k];
  float beta = 0.f;
  #pragma unroll
  for (int k = 2; k < NBIN; ++k) beta += p[k];
  comb[id] = 0.5f * (p[0] + p[1]) + beta * (1.f / 9.f);
}

// ---------------- K3: activity conv + sigmoid + interp + adaptive grid ----------------
__device__ __forceinline__ float wave_sum_f(float v) {
  #pragma unroll
  for (int off = 1; off < 64; off <<= 1) v += __shfl_xor(v, off);
  return v;
}
__device__ __forceinline__ int wave_sum_i(int v) {
  #pragma unroll
  for (int off = 1; off < 64; off <<= 1) v += __shfl_xor(v, off);
  return v;
}

__global__ __launch_bounds__(256) void act_grid(const float* __restrict__ comb,
    const float* __restrict__ aw1, const float* __restrict__ ab1,
    const float* __restrict__ ag,  const float* __restrict__ abt,
    const float* __restrict__ am,  const float* __restrict__ av,
    const float* __restrict__ aw2, const float* __restrict__ ab2,
    float* __restrict__ out_grid, float* __restrict__ out_acti,
    int* __restrict__ ends_i, int* __restrict__ grid_i) {
  int b = blockIdx.x;
  __shared__ float cl[CIN * NFR];
  __shared__ float actL[NFR];
  __shared__ float aiL[P];
  __shared__ float fL[P];
  __shared__ int   giL[P];
  __shared__ int   sI[P];
  __shared__ float red[1];
  for (int i = threadIdx.x; i < CIN * NFR; i += 256) cl[i] = comb[b * CIN * NFR + i];
  __syncthreads();
  int t = threadIdx.x;
  if (t < NFR) {
    float z = ab2[0];
    for (int o = 0; o < 11; ++o) {
      float s = ab1[o];
      for (int i = 0; i < CIN; ++i) {
        const float* wr = aw1 + o * 66 + i * 3;
        const float* crow = cl + i * NFR;
        if (t > 0)       s = fmaf(wr[0], crow[t - 1], s);
        s = fmaf(wr[1], crow[t], s);
        if (t < NFR - 1) s = fmaf(wr[2], crow[t + 1], s);
      }
      float rs = 1.0f / sqrtf(av[o] + 1e-5f);
      float y = (s - am[o]) * rs * ag[o] + abt[o];
      y = fmaxf(y, 0.f);
      z = fmaf(aw2[o], y, z);
    }
    actL[t] = 1.f / (1.f + expf(-z));
  }
  __syncthreads();
  if (t < P) {
    float ai = 0.5f * (actL[2 * t] + actL[2 * t + 1]);
    aiL[t] = ai;
    out_acti[b * P + t] = ai;
    fL[t] = 1.f / (ai + 1e-6f);
  }
  __syncthreads();
  if (t < 64) {
    float v = fL[t] + ((t + 64 < P) ? fL[t + 64] : 0.f);
    v = wave_sum_f(v);
    if (t == 0) red[0] = v;
  }
  __syncthreads();
  float sw = red[0];
  if (t < P) {
    float gg = (fL[t] / sw) * 5000.f;
    gg = fminf(fmaxf(gg, 10.f), 100.f);
    fL[t] = gg;
  }
  __syncthreads();
  if (t < 64) {
    float v = fL[t] + ((t + 64 < P) ? fL[t + 64] : 0.f);
    v = wave_sum_f(v);
    if (t == 0) red[0] = v;
  }
  __syncthreads();
  float r = 5000.f / red[0];
  if (t < P) giL[t] = (int)rintf(fL[t] * r);
  __syncthreads();
  if (t < 64) {
    int v = giL[t] + ((t + 64 < P) ? giL[t + 64] : 0);
    v = wave_sum_i(v);
    if (t == 0) red[0] = __int_as_float(v);
  }
  __syncthreads();
  if (t == P - 1) giL[P - 1] += 5000 - __float_as_int(red[0]);
  __syncthreads();
  if (t < P) giL[t] = min(max(giL[t], 10), 100);
  __syncthreads();
  if (t < 64) {
    int v = giL[t] + ((t + 64 < P) ? giL[t + 64] : 0);
    v = wave_sum_i(v);
    if (t == 0) red[0] = __int_as_float(v);
  }
  __syncthreads();
  if (t == P - 1) giL[P - 1] += 5000 - __float_as_int(red[0]);
  __syncthreads();
  if (t < P) sI[t] = max(giL[t], 10);
  __syncthreads();
  #pragma unroll
  for (int off = 1; off < P; off <<= 1) {
    int v = 0;
    if (t < P && t >= off) v = sI[t - off];
    __syncthreads();
    if (t < P) sI[t] += v;
    __syncthreads();
  }
  if (t < P) {
    int g = max(giL[t], 10);
    out_grid[b * P + t] = (float)g;
    grid_i[b * P + t] = g;
    ends_i[b * P + t] = sI[t];
  }
}

// ---------------- K4: fused multi-scale conv via MFMA, one scale per block ----------------
template <int KS, int FB, int SBASE>
__device__ __forceinline__ void scale_body(const unsigned short* __restrict__ xs,
                                           const unsigned short* __restrict__ pw,
                                           const float* __restrict__ Aff,
                                           const float* __restrict__ Bff,
                                           unsigned short* __restrict__ feats,
                                           int b, int t0, int wt0, int lane) {
  constexpr int PAD = (KS - 1) / 2;
  const int n = lane & 15, q = lane >> 4;
  f32x4 acc[3][4];
  #pragma unroll
  for (int ot = 0; ot < 3; ++ot)
    #pragma unroll
    for (int ti = 0; ti < 4; ++ti)
      acc[ot][ti] = (f32x4){0.f, 0.f, 0.f, 0.f};

  const unsigned short* pws = pw + (size_t)FB * 512 + lane * 8;
  #pragma unroll 1
  for (int k = 0; k < KS; ++k) {
    bf16x8 A0 = *(const bf16x8*)(pws + (size_t)(k * 3 + 0) * 512);
    bf16x8 A1 = *(const bf16x8*)(pws + (size_t)(k * 3 + 1) * 512);
    bf16x8 A2 = *(const bf16x8*)(pws + (size_t)(k * 3 + 2) * 512);
    int rbase = 24 - PAD + k + wt0 + n;
    #pragma unroll
    for (int ti = 0; ti < 4; ++ti) {
      bf16x8 Bf = *(const bf16x8*)(xs + (rbase + ti * 16) * RSTRIDE + q * 8);
      acc[0][ti] = __builtin_amdgcn_mfma_f32_16x16x32_bf16(A0, Bf, acc[0][ti], 0, 0, 0);
      acc[1][ti] = __builtin_amdgcn_mfma_f32_16x16x32_bf16(A1, Bf, acc[1][ti], 0, 0, 0);
      acc[2][ti] = __builtin_amdgcn_mfma_f32_16x16x32_bf16(A2, Bf, acc[2][ti], 0, 0, 0);
    }
  }
  #pragma unroll
  for (int ot = 0; ot < 3; ++ot) {
    int obase = ot * 16 + q * 4;
    if (obase < OC) {
      float Av0 = Aff[SBASE + obase + 0], Bv0 = Bff[SBASE + obase + 0];
      float Av1 = Aff[SBASE + obase + 1], Bv1 = Bff[SBASE + obase + 1];
      float Av2 = Aff[SBASE + obase + 2], Bv2 = Bff[SBASE + obase + 2];
      float Av3 = Aff[SBASE + obase + 3], Bv3 = Bff[SBASE + obase + 3];
      #pragma unroll
      for (int ti = 0; ti < 4; ++ti) {
        int tt = t0 + wt0 + ti * 16 + n;
        if (tt < T) {
          US4 pk;
          pk.a = f2bf(fast_elu(fmaf(acc[ot][ti][0], Av0, Bv0)));
          pk.b = f2bf(fast_elu(fmaf(acc[ot][ti][1], Av1, Bv1)));
          pk.c = f2bf(fast_elu(fmaf(acc[ot][ti][2], Av2, Bv2)));
          pk.d = f2bf(fast_elu(fmaf(acc[ot][ti][3], Av3, Bv3)));
          *reinterpret_cast<US4*>(feats + (size_t)(b * T + tt) * FC + SBASE + obase) = pk;
        }
      }
    }
  }
}

__global__ __launch_bounds__(256) void conv_mfma(const float* __restrict__ x,
                                                 const unsigned short* __restrict__ pw,
                                                 const float* __restrict__ Aff,
                                                 const float* __restrict__ Bff,
                                                 unsigned short* __restrict__ feats) {
  __shared__ unsigned short xs[ROWS * RSTRIDE];  // 24320 B, [t][h] bf16
  int b = blockIdx.y, t0 = blockIdx.x * 256;
  for (int idx = threadIdx.x; idx < CIN * ROWS; idx += 256) {
    int h = idx / ROWS, tl = idx - h * ROWS;
    int gt = t0 - 24 + tl;
    float v = (gt >= 0 && gt < T) ? x[(size_t)(b * CIN + h) * T + gt] : 0.f;
    xs[tl * RSTRIDE + h] = f2bf(v);
  }
  for (int idx = threadIdx.x; idx < 10 * ROWS; idx += 256) {
    int c = idx / ROWS, tl = idx - c * ROWS;
    xs[tl * RSTRIDE + 22 + c] = 0;
  }
  __syncthreads();
  int wv = threadIdx.x >> 6, lane = threadIdx.x & 63;
  int wt0 = wv * 64;
  if (blockIdx.z == 0)
    scale_body<9, 0, 0>(xs, pw, Aff, Bff, feats, b, t0, wt0, lane);
  else if (blockIdx.z == 1)
    scale_body<25, 27, 40>(xs, pw, Aff, Bff, feats, b, t0, wt0, lane);
  else
    scale_body<49, 102, 80>(xs, pw, Aff, Bff, feats, b, t0, wt0, lane);
}

// ---------------- K5: ragged avg+max pool + projection ----------------
// 256 threads = 30 channel-quads x 8 time-slices; uint2 (4 bf16) loads.
__global__ __launch_bounds__(256) void pool_proj(const unsigned short* __restrict__ feats,
                                                 const int* __restrict__ ends_i,
                                                 const int* __restrict__ grid_i,
                                                 const float* __restrict__ proj_w,
                                                 const float* __restrict__ proj_b,
                                                 float* __restrict__ out_emb) {
  int bp = blockIdx.x;
  int b = bp / P;
  int end = ends_i[bp];
  int gr = grid_i[bp];
  int start = end - gr;
  __shared__ float lds_s[8 * FC];
  __shared__ float lds_m[8 * FC];
  __shared__ float pooled[FC];
  int tid = threadIdx.x;
  bool valid = (end <= T);
  int g = tid % 30;     // channel quad
  int r = tid / 30;     // time slice 0..8 (r==8 for tid 240..255 -> idle)
  if (valid && r < 8) {
    float s0 = 0.f, s1 = 0.f, s2 = 0.f, s3 = 0.f;
    float m0 = -INFINITY, m1 = -INFINITY, m2 = -INFINITY, m3 = -INFINITY;
    const unsigned short* base = feats + (size_t)(b * T + start) * FC + g * 4;
    for (int i = r; i < gr; i += 8) {
      uint2 u = *reinterpret_cast<const uint2*>(base + (size_t)i * FC);
      float v0 = bf2f((unsigned short)(u.x & 0xffffu));
      float v1 = bf2f((unsigned short)(u.x >> 16));
      float v2 = bf2f((unsigned short)(u.y & 0xffffu));
      float v3 = bf2f((unsigned short)(u.y >> 16));
      s0 += v0; s1 += v1; s2 += v2; s3 += v3;
      m0 = fmaxf(m0, v0); m1 = fmaxf(m1, v1); m2 = fmaxf(m2, v2); m3 = fmaxf(m3, v3);
    }
    lds_s[r * FC + g * 4 + 0] = s0; lds_s[r * FC + g * 4 + 1] = s1;
    lds_s[r * FC + g * 4 + 2] = s2; lds_s[r * FC + g * 4 + 3] = s3;
    lds_m[r * FC + g * 4 + 0] = m0; lds_m[r * FC + g * 4 + 1] = m1;
    lds_m[r * FC + g * 4 + 2] = m2; lds_m[r * FC + g * 4 + 3] = m3;
  }
  __syncthreads();
  if (tid < FC) {
    if (valid) {
      float s = 0.f, mx = -INFINITY;
      #pragma unroll
      for (int rr = 0; rr < 8; ++rr) {
        s += lds_s[rr * FC + tid];
        mx = fmaxf(mx, lds_m[rr * FC + tid]);
      }
      pooled[tid] = s / (float)gr + mx;
    } else {
      pooled[tid] = 0.f;
    }
  }
  __syncthreads();
  if (tid < EMB) {
    float e = proj_b[tid];
    const float* wr = proj_w + tid * FC;
    #pragma unroll 8
    for (int c = 0; c < FC; ++c) e = fmaf(wr[c], pooled[c], e);
    out_emb[(size_t)bp * EMB + tid] = e;
  }
}

extern "C" void kernel_launch(void* const* d_in, const int* in_sizes, int n_in,
                              void* d_out, int out_size, void* d_ws, size_t ws_size,
                              hipStream_t stream) {
  const float* x = (const float*)d_in[0];
  const float* aw1 = (const float*)d_in[25];
  const float* ab1 = (const float*)d_in[26];
  const float* ag  = (const float*)d_in[27];
  const float* abt = (const float*)d_in[28];
  const float* am  = (const float*)d_in[29];
  const float* av  = (const float*)d_in[30];
  const float* aw2 = (const float*)d_in[31];
  const float* ab2 = (const float*)d_in[32];
  const float* proj_w = (const float*)d_in[33];
  const float* proj_b = (const float*)d_in[34];

  float* wsf = (float*)d_ws;
  float* A    = wsf;                 // 120
  float* Bc   = wsf + 120;           // 120
  float* tcs  = wsf + 240;           // 1408
  float* tsn  = wsf + 1648;          // 1408
  float* comb = wsf + 3056;          // 140800
  int* ends_i = (int*)(wsf + 143856);       // 3200
  int* grid_i = (int*)(wsf + 147056);       // 3200
  unsigned short* pw = (unsigned short*)(wsf + 150256);     // 127488 ushorts
  unsigned short* feats = (unsigned short*)(wsf + 214000);  // 19.2M ushorts (38.4 MB)

  float* out      = (float*)d_out;
  float* out_emb  = out;             // 204800
  float* out_grid = out + 204800;    // 3200
  float* out_acti = out + 208000;    // 3200

  SetupArgs sa;
  for (int s = 0; s < 3; ++s) {
    sa.w1[s] = (const float*)d_in[1 + 8 * s];
    sa.b1[s] = (const float*)d_in[2 + 8 * s];
    sa.w2[s] = (const float*)d_in[3 + 8 * s];
    sa.b2[s] = (const float*)d_in[4 + 8 * s];
    sa.g[s]  = (const float*)d_in[5 + 8 * s];
    sa.bt[s] = (const float*)d_in[6 + 8 * s];
    sa.m[s]  = (const float*)d_in[7 + 8 * s];
    sa.v[s]  = (const float*)d_in[8 + 8 * s];
  }
  sa.pw = pw; sa.A = A; sa.Bc = Bc; sa.tcs = tcs; sa.tsn = tsn;

  setup_all<<<505, 256, 0, stream>>>(sa);
  stft_comb<<<(B * CIN * NFR) / 256, 256, 0, stream>>>(x, tcs, tsn, comb);
  act_grid<<<B, 256, 0, stream>>>(comb, aw1, ab1, ag, abt, am, av, aw2, ab2,
                                  out_grid, out_acti, ends_i, grid_i);
  conv_mfma<<<dim3(20, B, 3), 256, 0, stream>>>(x, pw, A, Bc, feats);
  pool_proj<<<B * P, 256, 0, stream>>>(feats, ends_i, grid_i, proj_w, proj_b, out_emb);
}

// Round 7
// 320.195 us; speedup vs baseline: 4.6288x; 1.1338x over previous
//
#include <hip/hip_runtime.h>
#include <math.h>

#define B 32
#define CIN 22
#define T 5000
#define EMB 64
#define P 100
#define HOP 25
#define OC 40
#define FC 120
#define NBIN 11   // rfft bins 5..15
#define NFR 200

#define ROWS 304      // 256-t chunk + 24 halo each side
#define RSTRIDE 40    // ushorts per xs row (80 B = 20 dwords)

#define XPAD 5128     // reflect-padded x row: x[-64 .. 5063]

typedef unsigned short ushort_t;
typedef __attribute__((ext_vector_type(8))) short bf16x8;
typedef __attribute__((ext_vector_type(4))) float f32x4;
struct __align__(8) US4 { unsigned short a, b, c, d; };

__device__ __forceinline__ unsigned short f2bf(float f) {
  unsigned u = __float_as_uint(f);
  unsigned r = (u + 0x7FFFu + ((u >> 16) & 1u)) >> 16;
  return (unsigned short)r;
}
__device__ __forceinline__ float bf2f(unsigned short u) {
  return __uint_as_float(((unsigned)u) << 16);
}
__device__ __forceinline__ float fast_elu(float y) {
  return y > 0.f ? y : (__builtin_amdgcn_exp2f(y * 1.44269504088896340736f) - 1.0f);
}

// ---------------- K1: merged setup (fused-weight pack + twiddles + affine) ----------------
struct SetupArgs {
  const float* w1[3]; const float* b1[3]; const float* w2[3]; const float* b2[3];
  const float* g[3];  const float* bt[3]; const float* m[3];  const float* v[3];
  unsigned short* pw;
  float* A; float* Bc; float* tcs; float* tsn;
};

__global__ __launch_bounds__(256) void setup_all(SetupArgs args) {
  if (blockIdx.x < 498) {
    int id = blockIdx.x * 256 + threadIdx.x;
    int s, KS, fbase, idl;
    if (id < 13824)       { s = 0; KS = 9;  fbase = 0;   idl = id; }
    else if (id < 52224)  { s = 1; KS = 25; fbase = 27;  idl = id - 13824; }
    else                  { s = 2; KS = 49; fbase = 102; idl = id - 52224; }
    int fi = idl >> 9, rem = idl & 511;
    int lane = rem >> 3, j = rem & 7;
    int k = fi / 3, ot = fi - k * 3;
    int m = lane & 15, h = ((lane >> 4) << 3) + j;
    int o = ot * 16 + m;
    float val = 0.f;
    if (h < CIN && o < OC) {
      const float* w1 = args.w1[s];
      const float* w2 = args.w2[s];
      for (int i = 0; i < OC; ++i)
        val = fmaf(w2[(o * OC + i) * CIN + h], w1[i * KS + k], val);
    }
    args.pw[(size_t)(fbase + fi) * 512 + rem] = f2bf(val);
  } else if (blockIdx.x < 504) {
    int id = (blockIdx.x - 498) * 256 + threadIdx.x;
    if (id < NBIN * 128) {
      int k = id / 128 + 5, n = id - (id / 128) * 128;
      const double PI = 3.14159265358979323846;
      double ang = -2.0 * PI * (double)(k * n) / 128.0;
      double win = 0.5 * (1.0 - cos(2.0 * PI * (double)n / 128.0));
      args.tcs[id] = (float)(cos(ang) * win);
      args.tsn[id] = (float)(sin(ang) * win);
    }
  } else {
    int id = threadIdx.x;
    if (id < 120) {
      int s = id / 40, o = id - s * 40;
      const float* w2 = args.w2[s];
      float sc = args.g[s][o] / sqrtf(args.v[s][o] + 1e-5f);
      float cc = args.b2[s][o];
      for (int i = 0; i < OC; ++i) {
        float sh = 0.f;
        for (int h = 0; h < CIN; ++h) sh += w2[(o * OC + i) * CIN + h];
        cc = fmaf(args.b1[s][i], sh, cc);
      }
      args.A[id] = sc;
      args.Bc[id] = cc * sc + (args.bt[s][o] - args.m[s][o] * sc);
    }
  }
}

// ---------------- K2: STFT power -> comb (one block per (b,c) row, LDS-staged) ----------------
__global__ __launch_bounds__(256) void stft_comb(const float* __restrict__ x,
                                                 const float* __restrict__ tcg,
                                                 const float* __restrict__ tsg,
                                                 float* __restrict__ comb) {
  __shared__ float xsh[XPAD];            // 20.5 KB reflect-padded row
  __shared__ float tw[NBIN * 128 * 2];   // 22.5 KB interleaved cos/sin
  int bc = blockIdx.x;
  const float* xr = x + (size_t)bc * T;
  int tid = threadIdx.x;
  for (int i = tid; i < NBIN * 128; i += 256) {
    tw[2 * i]     = tcg[i];
    tw[2 * i + 1] = tsg[i];
  }
  for (int i = tid; i < XPAD; i += 256) {
    int mm = i - 64;
    mm = (mm < 0) ? -mm : mm;
    mm = (mm >= T) ? (2 * T - 2 - mm) : mm;
    xsh[i] = xr[mm];
  }
  __syncthreads();
  int fr = tid;
  if (fr < NFR) {
    float cr[NBIN], ci[NBIN];
    #pragma unroll
    for (int k = 0; k < NBIN; ++k) { cr[k] = 0.f; ci[k] = 0.f; }
    const float* xw = xsh + fr * HOP;
    for (int n = 0; n < 128; ++n) {
      float xv = xw[n];
      const float* twn = tw + 2 * n;
      #pragma unroll
      for (int k = 0; k < NBIN; ++k) {
        float2 w = *reinterpret_cast<const float2*>(twn + 256 * k);
        cr[k] = fmaf(xv, w.x, cr[k]);
        ci[k] = fmaf(xv, w.y, ci[k]);
      }
    }
    float p[NBIN];
    #pragma unroll
    for (int k = 0; k < NBIN; ++k) p[k] = cr[k] * cr[k] + ci[k] * ci[k];
    float beta = 0.f;
    #pragma unroll
    for (int k = 2; k < NBIN; ++k) beta += p[k];
    comb[bc * NFR + fr] = 0.5f * (p[0] + p[1]) + beta * (1.f / 9.f);
  }
}

// ---------------- K3: activity conv + sigmoid + interp + adaptive grid ----------------
__device__ __forceinline__ float wave_sum_f(float v) {
  #pragma unroll
  for (int off = 1; off < 64; off <<= 1) v += __shfl_xor(v, off);
  return v;
}
__device__ __forceinline__ int wave_sum_i(int v) {
  #pragma unroll
  for (int off = 1; off < 64; off <<= 1) v += __shfl_xor(v, off);
  return v;
}

__global__ __launch_bounds__(256) void act_grid(const float* __restrict__ comb,
    const float* __restrict__ aw1, const float* __restrict__ ab1,
    const float* __restrict__ ag,  const float* __restrict__ abt,
    const float* __restrict__ am,  const float* __restrict__ av,
    const float* __restrict__ aw2, const float* __restrict__ ab2,
    float* __restrict__ out_grid, float* __restrict__ out_acti,
    int* __restrict__ ends_i, int* __restrict__ grid_i) {
  int b = blockIdx.x;
  __shared__ float cl[CIN * NFR];
  __shared__ float actL[NFR];
  __shared__ float aiL[P];
  __shared__ float fL[P];
  __shared__ int   giL[P];
  __shared__ int   sI[P];
  __shared__ float red[1];
  for (int i = threadIdx.x; i < CIN * NFR; i += 256) cl[i] = comb[b * CIN * NFR + i];
  __syncthreads();
  int t = threadIdx.x;
  if (t < NFR) {
    float z = ab2[0];
    for (int o = 0; o < 11; ++o) {
      float s = ab1[o];
      for (int i = 0; i < CIN; ++i) {
        const float* wr = aw1 + o * 66 + i * 3;
        const float* crow = cl + i * NFR;
        if (t > 0)       s = fmaf(wr[0], crow[t - 1], s);
        s = fmaf(wr[1], crow[t], s);
        if (t < NFR - 1) s = fmaf(wr[2], crow[t + 1], s);
      }
      float rs = 1.0f / sqrtf(av[o] + 1e-5f);
      float y = (s - am[o]) * rs * ag[o] + abt[o];
      y = fmaxf(y, 0.f);
      z = fmaf(aw2[o], y, z);
    }
    actL[t] = 1.f / (1.f + expf(-z));
  }
  __syncthreads();
  if (t < P) {
    float ai = 0.5f * (actL[2 * t] + actL[2 * t + 1]);
    aiL[t] = ai;
    out_acti[b * P + t] = ai;
    fL[t] = 1.f / (ai + 1e-6f);
  }
  __syncthreads();
  if (t < 64) {
    float v = fL[t] + ((t + 64 < P) ? fL[t + 64] : 0.f);
    v = wave_sum_f(v);
    if (t == 0) red[0] = v;
  }
  __syncthreads();
  float sw = red[0];
  if (t < P) {
    float gg = (fL[t] / sw) * 5000.f;
    gg = fminf(fmaxf(gg, 10.f), 100.f);
    fL[t] = gg;
  }
  __syncthreads();
  if (t < 64) {
    float v = fL[t] + ((t + 64 < P) ? fL[t + 64] : 0.f);
    v = wave_sum_f(v);
    if (t == 0) red[0] = v;
  }
  __syncthreads();
  float r = 5000.f / red[0];
  if (t < P) giL[t] = (int)rintf(fL[t] * r);
  __syncthreads();
  if (t < 64) {
    int v = giL[t] + ((t + 64 < P) ? giL[t + 64] : 0);
    v = wave_sum_i(v);
    if (t == 0) red[0] = __int_as_float(v);
  }
  __syncthreads();
  if (t == P - 1) giL[P - 1] += 5000 - __float_as_int(red[0]);
  __syncthreads();
  if (t < P) giL[t] = min(max(giL[t], 10), 100);
  __syncthreads();
  if (t < 64) {
    int v = giL[t] + ((t + 64 < P) ? giL[t + 64] : 0);
    v = wave_sum_i(v);
    if (t == 0) red[0] = __int_as_float(v);
  }
  __syncthreads();
  if (t == P - 1) giL[P - 1] += 5000 - __float_as_int(red[0]);
  __syncthreads();
  if (t < P) sI[t] = max(giL[t], 10);
  __syncthreads();
  #pragma unroll
  for (int off = 1; off < P; off <<= 1) {
    int v = 0;
    if (t < P && t >= off) v = sI[t - off];
    __syncthreads();
    if (t < P) sI[t] += v;
    __syncthreads();
  }
  if (t < P) {
    int g = max(giL[t], 10);
    out_grid[b * P + t] = (float)g;
    grid_i[b * P + t] = g;
    ends_i[b * P + t] = sI[t];
  }
}

// ---------------- K4: fused multi-scale conv via MFMA, one scale per block ----------------
template <int KS, int FB, int SBASE>
__device__ __forceinline__ void scale_body(const unsigned short* __restrict__ xs,
                                           const unsigned short* __restrict__ pw,
                                           const float* __restrict__ Aff,
                                           const float* __restrict__ Bff,
                                           unsigned short* __restrict__ feats,
                                           int b, int t0, int wt0, int lane) {
  constexpr int PAD = (KS - 1) / 2;
  const int n = lane & 15, q = lane >> 4;
  f32x4 acc[3][4];
  #pragma unroll
  for (int ot = 0; ot < 3; ++ot)
    #pragma unroll
    for (int ti = 0; ti < 4; ++ti)
      acc[ot][ti] = (f32x4){0.f, 0.f, 0.f, 0.f};

  const unsigned short* pws = pw + (size_t)FB * 512 + lane * 8;
  #pragma unroll 1
  for (int k = 0; k < KS; ++k) {
    bf16x8 A0 = *(const bf16x8*)(pws + (size_t)(k * 3 + 0) * 512);
    bf16x8 A1 = *(const bf16x8*)(pws + (size_t)(k * 3 + 1) * 512);
    bf16x8 A2 = *(const bf16x8*)(pws + (size_t)(k * 3 + 2) * 512);
    int rbase = 24 - PAD + k + wt0 + n;
    #pragma unroll
    for (int ti = 0; ti < 4; ++ti) {
      bf16x8 Bf = *(const bf16x8*)(xs + (rbase + ti * 16) * RSTRIDE + q * 8);
      acc[0][ti] = __builtin_amdgcn_mfma_f32_16x16x32_bf16(A0, Bf, acc[0][ti], 0, 0, 0);
      acc[1][ti] = __builtin_amdgcn_mfma_f32_16x16x32_bf16(A1, Bf, acc[1][ti], 0, 0, 0);
      acc[2][ti] = __builtin_amdgcn_mfma_f32_16x16x32_bf16(A2, Bf, acc[2][ti], 0, 0, 0);
    }
  }
  #pragma unroll
  for (int ot = 0; ot < 3; ++ot) {
    int obase = ot * 16 + q * 4;
    if (obase < OC) {
      float Av0 = Aff[SBASE + obase + 0], Bv0 = Bff[SBASE + obase + 0];
      float Av1 = Aff[SBASE + obase + 1], Bv1 = Bff[SBASE + obase + 1];
      float Av2 = Aff[SBASE + obase + 2], Bv2 = Bff[SBASE + obase + 2];
      float Av3 = Aff[SBASE + obase + 3], Bv3 = Bff[SBASE + obase + 3];
      #pragma unroll
      for (int ti = 0; ti < 4; ++ti) {
        int tt = t0 + wt0 + ti * 16 + n;
        if (tt < T) {
          US4 pk;
          pk.a = f2bf(fast_elu(fmaf(acc[ot][ti][0], Av0, Bv0)));
          pk.b = f2bf(fast_elu(fmaf(acc[ot][ti][1], Av1, Bv1)));
          pk.c = f2bf(fast_elu(fmaf(acc[ot][ti][2], Av2, Bv2)));
          pk.d = f2bf(fast_elu(fmaf(acc[ot][ti][3], Av3, Bv3)));
          *reinterpret_cast<US4*>(feats + (size_t)(b * T + tt) * FC + SBASE + obase) = pk;
        }
      }
    }
  }
}

__global__ __launch_bounds__(256) void conv_mfma(const float* __restrict__ x,
                                                 const unsigned short* __restrict__ pw,
                                                 const float* __restrict__ Aff,
                                                 const float* __restrict__ Bff,
                                                 unsigned short* __restrict__ feats) {
  __shared__ unsigned short xs[ROWS * RSTRIDE];  // 24320 B, [t][h] bf16
  int b = blockIdx.y, t0 = blockIdx.x * 256;
  for (int idx = threadIdx.x; idx < CIN * ROWS; idx += 256) {
    int h = idx / ROWS, tl = idx - h * ROWS;
    int gt = t0 - 24 + tl;
    float v = (gt >= 0 && gt < T) ? x[(size_t)(b * CIN + h) * T + gt] : 0.f;
    xs[tl * RSTRIDE + h] = f2bf(v);
  }
  for (int idx = threadIdx.x; idx < 10 * ROWS; idx += 256) {
    int c = idx / ROWS, tl = idx - c * ROWS;
    xs[tl * RSTRIDE + 22 + c] = 0;
  }
  __syncthreads();
  int wv = threadIdx.x >> 6, lane = threadIdx.x & 63;
  int wt0 = wv * 64;
  if (blockIdx.z == 0)
    scale_body<9, 0, 0>(xs, pw, Aff, Bff, feats, b, t0, wt0, lane);
  else if (blockIdx.z == 1)
    scale_body<25, 27, 40>(xs, pw, Aff, Bff, feats, b, t0, wt0, lane);
  else
    scale_body<49, 102, 80>(xs, pw, Aff, Bff, feats, b, t0, wt0, lane);
}

// ---------------- K5: ragged avg+max pool + projection ----------------
__global__ __launch_bounds__(256) void pool_proj(const unsigned short* __restrict__ feats,
                                                 const int* __restrict__ ends_i,
                                                 const int* __restrict__ grid_i,
                                                 const float* __restrict__ proj_w,
                                                 const float* __restrict__ proj_b,
                                                 float* __restrict__ out_emb) {
  int bp = blockIdx.x;
  int b = bp / P;
  int end = ends_i[bp];
  int gr = grid_i[bp];
  int start = end - gr;
  __shared__ float lds_s[8 * FC];
  __shared__ float lds_m[8 * FC];
  __shared__ float pooled[FC];
  int tid = threadIdx.x;
  bool valid = (end <= T);
  int g = tid % 30;     // channel quad
  int r = tid / 30;     // time slice 0..8 (r==8 -> idle)
  if (valid && r < 8) {
    float s0 = 0.f, s1 = 0.f, s2 = 0.f, s3 = 0.f;
    float m0 = -INFINITY, m1 = -INFINITY, m2 = -INFINITY, m3 = -INFINITY;
    const unsigned short* base = feats + (size_t)(b * T + start) * FC + g * 4;
    for (int i = r; i < gr; i += 8) {
      uint2 u = *reinterpret_cast<const uint2*>(base + (size_t)i * FC);
      float v0 = bf2f((unsigned short)(u.x & 0xffffu));
      float v1 = bf2f((unsigned short)(u.x >> 16));
      float v2 = bf2f((unsigned short)(u.y & 0xffffu));
      float v3 = bf2f((unsigned short)(u.y >> 16));
      s0 += v0; s1 += v1; s2 += v2; s3 += v3;
      m0 = fmaxf(m0, v0); m1 = fmaxf(m1, v1); m2 = fmaxf(m2, v2); m3 = fmaxf(m3, v3);
    }
    lds_s[r * FC + g * 4 + 0] = s0; lds_s[r * FC + g * 4 + 1] = s1;
    lds_s[r * FC + g * 4 + 2] = s2; lds_s[r * FC + g * 4 + 3] = s3;
    lds_m[r * FC + g * 4 + 0] = m0; lds_m[r * FC + g * 4 + 1] = m1;
    lds_m[r * FC + g * 4 + 2] = m2; lds_m[r * FC + g * 4 + 3] = m3;
  }
  __syncthreads();
  if (tid < FC) {
    if (valid) {
      float s = 0.f, mx = -INFINITY;
      #pragma unroll
      for (int rr = 0; rr < 8; ++rr) {
        s += lds_s[rr * FC + tid];
        mx = fmaxf(mx, lds_m[rr * FC + tid]);
      }
      pooled[tid] = s / (float)gr + mx;
    } else {
      pooled[tid] = 0.f;
    }
  }
  __syncthreads();
  if (tid < EMB) {
    float e = proj_b[tid];
    const float* wr = proj_w + tid * FC;
    #pragma unroll 8
    for (int c = 0; c < FC; ++c) e = fmaf(wr[c], pooled[c], e);
    out_emb[(size_t)bp * EMB + tid] = e;
  }
}

extern "C" void kernel_launch(void* const* d_in, const int* in_sizes, int n_in,
                              void* d_out, int out_size, void* d_ws, size_t ws_size,
                              hipStream_t stream) {
  const float* x = (const float*)d_in[0];
  const float* aw1 = (const float*)d_in[25];
  const float* ab1 = (const float*)d_in[26];
  const float* ag  = (const float*)d_in[27];
  const float* abt = (const float*)d_in[28];
  const float* am  = (const float*)d_in[29];
  const float* av  = (const float*)d_in[30];
  const float* aw2 = (const float*)d_in[31];
  const float* ab2 = (const float*)d_in[32];
  const float* proj_w = (const float*)d_in[33];
  const float* proj_b = (const float*)d_in[34];

  float* wsf = (float*)d_ws;
  float* A    = wsf;                 // 120
  float* Bc   = wsf + 120;           // 120
  float* tcs  = wsf + 240;           // 1408
  float* tsn  = wsf + 1648;          // 1408
  float* comb = wsf + 3056;          // 140800
  int* ends_i = (int*)(wsf + 143856);       // 3200
  int* grid_i = (int*)(wsf + 147056);       // 3200
  unsigned short* pw = (unsigned short*)(wsf + 150256);     // 127488 ushorts
  unsigned short* feats = (unsigned short*)(wsf + 214000);  // 19.2M ushorts (38.4 MB)

  float* out      = (float*)d_out;
  float* out_emb  = out;             // 204800
  float* out_grid = out + 204800;    // 3200
  float* out_acti = out + 208000;    // 3200

  SetupArgs sa;
  for (int s = 0; s < 3; ++s) {
    sa.w1[s] = (const float*)d_in[1 + 8 * s];
    sa.b1[s] = (const float*)d_in[2 + 8 * s];
    sa.w2[s] = (const float*)d_in[3 + 8 * s];
    sa.b2[s] = (const float*)d_in[4 + 8 * s];
    sa.g[s]  = (const float*)d_in[5 + 8 * s];
    sa.bt[s] = (const float*)d_in[6 + 8 * s];
    sa.m[s]  = (const float*)d_in[7 + 8 * s];
    sa.v[s]  = (const float*)d_in[8 + 8 * s];
  }
  sa.pw = pw; sa.A = A; sa.Bc = Bc; sa.tcs = tcs; sa.tsn = tsn;

  setup_all<<<505, 256, 0, stream>>>(sa);
  stft_comb<<<B * CIN, 256, 0, stream>>>(x, tcs, tsn, comb);
  act_grid<<<B, 256, 0, stream>>>(comb, aw1, ab1, ag, abt, am, av, aw2, ab2,
                                  out_grid, out_acti, ends_i, grid_i);
  conv_mfma<<<dim3(20, B, 3), 256, 0, stream>>>(x, pw, A, Bc, feats);
  pool_proj<<<B * P, 256, 0, stream>>>(feats, ends_i, grid_i, proj_w, proj_b, out_emb);
}

// Round 8
// 315.203 us; speedup vs baseline: 4.7022x; 1.0158x over previous
//
#include <hip/hip_runtime.h>
#include <math.h>

#define B 32
#define CIN 22
#define T 5000
#define EMB 64
#define P 100
#define HOP 25
#define OC 40
#define FC 120
#define NBIN 11   // rfft bins 5..15
#define NFR 200

#define TCH 128       // conv t-chunk
#define CROWS 176     // TCH + 24 halo each side
#define RSTRIDE 40    // ushorts per xs row (80 B = 20 dwords)

#define XPAD 5128     // reflect-padded x row: x[-64 .. 5063]

typedef unsigned short ushort_t;
typedef __attribute__((ext_vector_type(8))) short bf16x8;
typedef __attribute__((ext_vector_type(4))) float f32x4;
struct __align__(8) US4 { unsigned short a, b, c, d; };

__device__ __forceinline__ unsigned short f2bf(float f) {
  unsigned u = __float_as_uint(f);
  unsigned r = (u + 0x7FFFu + ((u >> 16) & 1u)) >> 16;
  return (unsigned short)r;
}
__device__ __forceinline__ float bf2f(unsigned short u) {
  return __uint_as_float(((unsigned)u) << 16);
}
__device__ __forceinline__ float fast_elu(float y) {
  return y > 0.f ? y : (__builtin_amdgcn_exp2f(y * 1.44269504088896340736f) - 1.0f);
}

// ---------------- K1: merged setup (fused-weight pack + twiddles + affine) ----------------
struct SetupArgs {
  const float* w1[3]; const float* b1[3]; const float* w2[3]; const float* b2[3];
  const float* g[3];  const float* bt[3]; const float* m[3];  const float* v[3];
  unsigned short* pw;
  float* A; float* Bc; float* tcs; float* tsn;
};

__global__ __launch_bounds__(256) void setup_all(SetupArgs args) {
  if (blockIdx.x < 498) {
    int id = blockIdx.x * 256 + threadIdx.x;
    int s, KS, fbase, idl;
    if (id < 13824)       { s = 0; KS = 9;  fbase = 0;   idl = id; }
    else if (id < 52224)  { s = 1; KS = 25; fbase = 27;  idl = id - 13824; }
    else                  { s = 2; KS = 49; fbase = 102; idl = id - 52224; }
    int fi = idl >> 9, rem = idl & 511;
    int lane = rem >> 3, j = rem & 7;
    int k = fi / 3, ot = fi - k * 3;
    int m = lane & 15, h = ((lane >> 4) << 3) + j;
    int o = ot * 16 + m;
    float val = 0.f;
    if (h < CIN && o < OC) {
      const float* w1 = args.w1[s];
      const float* w2 = args.w2[s];
      for (int i = 0; i < OC; ++i)
        val = fmaf(w2[(o * OC + i) * CIN + h], w1[i * KS + k], val);
    }
    args.pw[(size_t)(fbase + fi) * 512 + rem] = f2bf(val);
  } else if (blockIdx.x < 504) {
    int id = (blockIdx.x - 498) * 256 + threadIdx.x;
    if (id < NBIN * 128) {
      int k = id / 128 + 5, n = id - (id / 128) * 128;
      const double PI = 3.14159265358979323846;
      double ang = -2.0 * PI * (double)(k * n) / 128.0;
      double win = 0.5 * (1.0 - cos(2.0 * PI * (double)n / 128.0));
      args.tcs[id] = (float)(cos(ang) * win);
      args.tsn[id] = (float)(sin(ang) * win);
    }
  } else {
    int id = threadIdx.x;
    if (id < 120) {
      int s = id / 40, o = id - s * 40;
      const float* w2 = args.w2[s];
      float sc = args.g[s][o] / sqrtf(args.v[s][o] + 1e-5f);
      float cc = args.b2[s][o];
      for (int i = 0; i < OC; ++i) {
        float sh = 0.f;
        for (int h = 0; h < CIN; ++h) sh += w2[(o * OC + i) * CIN + h];
        cc = fmaf(args.b1[s][i], sh, cc);
      }
      args.A[id] = sc;
      args.Bc[id] = cc * sc + (args.bt[s][o] - args.m[s][o] * sc);
    }
  }
}

// ---------------- K2: STFT power -> comb (one block per (b,c) row, LDS-staged) ----------------
__global__ __launch_bounds__(256) void stft_comb(const float* __restrict__ x,
                                                 const float* __restrict__ tcg,
                                                 const float* __restrict__ tsg,
                                                 float* __restrict__ comb) {
  __shared__ float xsh[XPAD];            // 20.5 KB reflect-padded row
  __shared__ float tw[NBIN * 128 * 2];   // 11.3 KB interleaved cos/sin
  int bc = blockIdx.x;
  const float* xr = x + (size_t)bc * T;
  int tid = threadIdx.x;
  for (int i = tid; i < NBIN * 128; i += 256) {
    tw[2 * i]     = tcg[i];
    tw[2 * i + 1] = tsg[i];
  }
  for (int i = tid; i < XPAD; i += 256) {
    int mm = i - 64;
    mm = (mm < 0) ? -mm : mm;
    mm = (mm >= T) ? (2 * T - 2 - mm) : mm;
    xsh[i] = xr[mm];
  }
  __syncthreads();
  int fr = tid;
  if (fr < NFR) {
    float cr[NBIN], ci[NBIN];
    #pragma unroll
    for (int k = 0; k < NBIN; ++k) { cr[k] = 0.f; ci[k] = 0.f; }
    const float* xw = xsh + fr * HOP;
    for (int n = 0; n < 128; ++n) {
      float xv = xw[n];
      const float* twn = tw + 2 * n;
      #pragma unroll
      for (int k = 0; k < NBIN; ++k) {
        float2 w = *reinterpret_cast<const float2*>(twn + 256 * k);
        cr[k] = fmaf(xv, w.x, cr[k]);
        ci[k] = fmaf(xv, w.y, ci[k]);
      }
    }
    float p[NBIN];
    #pragma unroll
    for (int k = 0; k < NBIN; ++k) p[k] = cr[k] * cr[k] + ci[k] * ci[k];
    float beta = 0.f;
    #pragma unroll
    for (int k = 2; k < NBIN; ++k) beta += p[k];
    comb[bc * NFR + fr] = 0.5f * (p[0] + p[1]) + beta * (1.f / 9.f);
  }
}

// ---------------- K3: activity conv + sigmoid + interp + adaptive grid ----------------
__device__ __forceinline__ float wave_sum_f(float v) {
  #pragma unroll
  for (int off = 1; off < 64; off <<= 1) v += __shfl_xor(v, off);
  return v;
}
__device__ __forceinline__ int wave_sum_i(int v) {
  #pragma unroll
  for (int off = 1; off < 64; off <<= 1) v += __shfl_xor(v, off);
  return v;
}

__global__ __launch_bounds__(256) void act_grid(const float* __restrict__ comb,
    const float* __restrict__ aw1, const float* __restrict__ ab1,
    const float* __restrict__ ag,  const float* __restrict__ abt,
    const float* __restrict__ am,  const float* __restrict__ av,
    const float* __restrict__ aw2, const float* __restrict__ ab2,
    float* __restrict__ out_grid, float* __restrict__ out_acti,
    int* __restrict__ ends_i, int* __restrict__ grid_i) {
  int b = blockIdx.x;
  __shared__ float cl[CIN * NFR];
  __shared__ float actL[NFR];
  __shared__ float aiL[P];
  __shared__ float fL[P];
  __shared__ int   giL[P];
  __shared__ int   sI[P];
  __shared__ float red[1];
  for (int i = threadIdx.x; i < CIN * NFR; i += 256) cl[i] = comb[b * CIN * NFR + i];
  __syncthreads();
  int t = threadIdx.x;
  if (t < NFR) {
    float z = ab2[0];
    for (int o = 0; o < 11; ++o) {
      float s = ab1[o];
      for (int i = 0; i < CIN; ++i) {
        const float* wr = aw1 + o * 66 + i * 3;
        const float* crow = cl + i * NFR;
        if (t > 0)       s = fmaf(wr[0], crow[t - 1], s);
        s = fmaf(wr[1], crow[t], s);
        if (t < NFR - 1) s = fmaf(wr[2], crow[t + 1], s);
      }
      float rs = 1.0f / sqrtf(av[o] + 1e-5f);
      float y = (s - am[o]) * rs * ag[o] + abt[o];
      y = fmaxf(y, 0.f);
      z = fmaf(aw2[o], y, z);
    }
    actL[t] = 1.f / (1.f + expf(-z));
  }
  __syncthreads();
  if (t < P) {
    float ai = 0.5f * (actL[2 * t] + actL[2 * t + 1]);
    aiL[t] = ai;
    out_acti[b * P + t] = ai;
    fL[t] = 1.f / (ai + 1e-6f);
  }
  __syncthreads();
  if (t < 64) {
    float v = fL[t] + ((t + 64 < P) ? fL[t + 64] : 0.f);
    v = wave_sum_f(v);
    if (t == 0) red[0] = v;
  }
  __syncthreads();
  float sw = red[0];
  if (t < P) {
    float gg = (fL[t] / sw) * 5000.f;
    gg = fminf(fmaxf(gg, 10.f), 100.f);
    fL[t] = gg;
  }
  __syncthreads();
  if (t < 64) {
    float v = fL[t] + ((t + 64 < P) ? fL[t + 64] : 0.f);
    v = wave_sum_f(v);
    if (t == 0) red[0] = v;
  }
  __syncthreads();
  float r = 5000.f / red[0];
  if (t < P) giL[t] = (int)rintf(fL[t] * r);
  __syncthreads();
  if (t < 64) {
    int v = giL[t] + ((t + 64 < P) ? giL[t + 64] : 0);
    v = wave_sum_i(v);
    if (t == 0) red[0] = __int_as_float(v);
  }
  __syncthreads();
  if (t == P - 1) giL[P - 1] += 5000 - __float_as_int(red[0]);
  __syncthreads();
  if (t < P) giL[t] = min(max(giL[t], 10), 100);
  __syncthreads();
  if (t < 64) {
    int v = giL[t] + ((t + 64 < P) ? giL[t + 64] : 0);
    v = wave_sum_i(v);
    if (t == 0) red[0] = __int_as_float(v);
  }
  __syncthreads();
  if (t == P - 1) giL[P - 1] += 5000 - __float_as_int(red[0]);
  __syncthreads();
  if (t < P) sI[t] = max(giL[t], 10);
  __syncthreads();
  #pragma unroll
  for (int off = 1; off < P; off <<= 1) {
    int v = 0;
    if (t < P && t >= off) v = sI[t - off];
    __syncthreads();
    if (t < P) sI[t] += v;
    __syncthreads();
  }
  if (t < P) {
    int g = max(giL[t], 10);
    out_grid[b * P + t] = (float)g;
    grid_i[b * P + t] = g;
    ends_i[b * P + t] = sI[t];
  }
}

// ---------------- K4: fused multi-scale conv via MFMA, all scales per block ----------------
// block covers 128 t; each t row's full 240B feats written by this block (no partial-line RMW)
template <int KS, int FB, int SBASE>
__device__ __forceinline__ void scale_body(const unsigned short* __restrict__ xs,
                                           const unsigned short* __restrict__ pw,
                                           const float* __restrict__ Aff,
                                           const float* __restrict__ Bff,
                                           unsigned short* __restrict__ feats,
                                           int b, int t0, int wt0, int lane) {
  constexpr int PAD = (KS - 1) / 2;
  const int n = lane & 15, q = lane >> 4;
  f32x4 acc[3][2];
  #pragma unroll
  for (int ot = 0; ot < 3; ++ot)
    #pragma unroll
    for (int ti = 0; ti < 2; ++ti)
      acc[ot][ti] = (f32x4){0.f, 0.f, 0.f, 0.f};

  const unsigned short* pws = pw + (size_t)FB * 512 + lane * 8;
  #pragma unroll 1
  for (int k = 0; k < KS; ++k) {
    bf16x8 A0 = *(const bf16x8*)(pws + (size_t)(k * 3 + 0) * 512);
    bf16x8 A1 = *(const bf16x8*)(pws + (size_t)(k * 3 + 1) * 512);
    bf16x8 A2 = *(const bf16x8*)(pws + (size_t)(k * 3 + 2) * 512);
    int rbase = 24 - PAD + k + wt0 + n;
    #pragma unroll
    for (int ti = 0; ti < 2; ++ti) {
      bf16x8 Bf = *(const bf16x8*)(xs + (rbase + ti * 16) * RSTRIDE + q * 8);
      acc[0][ti] = __builtin_amdgcn_mfma_f32_16x16x32_bf16(A0, Bf, acc[0][ti], 0, 0, 0);
      acc[1][ti] = __builtin_amdgcn_mfma_f32_16x16x32_bf16(A1, Bf, acc[1][ti], 0, 0, 0);
      acc[2][ti] = __builtin_amdgcn_mfma_f32_16x16x32_bf16(A2, Bf, acc[2][ti], 0, 0, 0);
    }
  }
  #pragma unroll
  for (int ot = 0; ot < 3; ++ot) {
    int obase = ot * 16 + q * 4;
    if (obase < OC) {
      float Av0 = Aff[SBASE + obase + 0], Bv0 = Bff[SBASE + obase + 0];
      float Av1 = Aff[SBASE + obase + 1], Bv1 = Bff[SBASE + obase + 1];
      float Av2 = Aff[SBASE + obase + 2], Bv2 = Bff[SBASE + obase + 2];
      float Av3 = Aff[SBASE + obase + 3], Bv3 = Bff[SBASE + obase + 3];
      #pragma unroll
      for (int ti = 0; ti < 2; ++ti) {
        int tt = t0 + wt0 + ti * 16 + n;
        if (tt < T) {
          US4 pk;
          pk.a = f2bf(fast_elu(fmaf(acc[ot][ti][0], Av0, Bv0)));
          pk.b = f2bf(fast_elu(fmaf(acc[ot][ti][1], Av1, Bv1)));
          pk.c = f2bf(fast_elu(fmaf(acc[ot][ti][2], Av2, Bv2)));
          pk.d = f2bf(fast_elu(fmaf(acc[ot][ti][3], Av3, Bv3)));
          *reinterpret_cast<US4*>(feats + (size_t)(b * T + tt) * FC + SBASE + obase) = pk;
        }
      }
    }
  }
}

__global__ __launch_bounds__(256) void conv_mfma(const float* __restrict__ x,
                                                 const unsigned short* __restrict__ pw,
                                                 const float* __restrict__ Aff,
                                                 const float* __restrict__ Bff,
                                                 unsigned short* __restrict__ feats) {
  __shared__ unsigned short xs[CROWS * RSTRIDE];  // 14080 B, [t][h] bf16
  int b = blockIdx.y, t0 = blockIdx.x * TCH;
  for (int idx = threadIdx.x; idx < CIN * CROWS; idx += 256) {
    int h = idx / CROWS, tl = idx - h * CROWS;
    int gt = t0 - 24 + tl;
    float v = (gt >= 0 && gt < T) ? x[(size_t)(b * CIN + h) * T + gt] : 0.f;
    xs[tl * RSTRIDE + h] = f2bf(v);
  }
  for (int idx = threadIdx.x; idx < 10 * CROWS; idx += 256) {
    int c = idx / CROWS, tl = idx - c * CROWS;
    xs[tl * RSTRIDE + 22 + c] = 0;
  }
  __syncthreads();
  int wv = threadIdx.x >> 6, lane = threadIdx.x & 63;
  int wt0 = wv * 32;
  scale_body<9, 0, 0>(xs, pw, Aff, Bff, feats, b, t0, wt0, lane);
  scale_body<25, 27, 40>(xs, pw, Aff, Bff, feats, b, t0, wt0, lane);
  scale_body<49, 102, 80>(xs, pw, Aff, Bff, feats, b, t0, wt0, lane);
}

// ---------------- K5: ragged avg+max pool + projection ----------------
__global__ __launch_bounds__(256) void pool_proj(const unsigned short* __restrict__ feats,
                                                 const int* __restrict__ ends_i,
                                                 const int* __restrict__ grid_i,
                                                 const float* __restrict__ proj_w,
                                                 const float* __restrict__ proj_b,
                                                 float* __restrict__ out_emb) {
  int bp = blockIdx.x;
  int b = bp / P;
  int end = ends_i[bp];
  int gr = grid_i[bp];
  int start = end - gr;
  __shared__ float lds_s[8 * FC];
  __shared__ float lds_m[8 * FC];
  __shared__ float pooled[FC];
  int tid = threadIdx.x;
  bool valid = (end <= T);
  int g = tid % 30;     // channel quad
  int r = tid / 30;     // time slice 0..8 (r==8 -> idle)
  if (valid && r < 8) {
    float s0 = 0.f, s1 = 0.f, s2 = 0.f, s3 = 0.f;
    float m0 = -INFINITY, m1 = -INFINITY, m2 = -INFINITY, m3 = -INFINITY;
    const unsigned short* base = feats + (size_t)(b * T + start) * FC + g * 4;
    for (int i = r; i < gr; i += 8) {
      uint2 u = *reinterpret_cast<const uint2*>(base + (size_t)i * FC);
      float v0 = bf2f((unsigned short)(u.x & 0xffffu));
      float v1 = bf2f((unsigned short)(u.x >> 16));
      float v2 = bf2f((unsigned short)(u.y & 0xffffu));
      float v3 = bf2f((unsigned short)(u.y >> 16));
      s0 += v0; s1 += v1; s2 += v2; s3 += v3;
      m0 = fmaxf(m0, v0); m1 = fmaxf(m1, v1); m2 = fmaxf(m2, v2); m3 = fmaxf(m3, v3);
    }
    lds_s[r * FC + g * 4 + 0] = s0; lds_s[r * FC + g * 4 + 1] = s1;
    lds_s[r * FC + g * 4 + 2] = s2; lds_s[r * FC + g * 4 + 3] = s3;
    lds_m[r * FC + g * 4 + 0] = m0; lds_m[r * FC + g * 4 + 1] = m1;
    lds_m[r * FC + g * 4 + 2] = m2; lds_m[r * FC + g * 4 + 3] = m3;
  }
  __syncthreads();
  if (tid < FC) {
    if (valid) {
      float s = 0.f, mx = -INFINITY;
      #pragma unroll
      for (int rr = 0; rr < 8; ++rr) {
        s += lds_s[rr * FC + tid];
        mx = fmaxf(mx, lds_m[rr * FC + tid]);
      }
      pooled[tid] = s / (float)gr + mx;
    } else {
      pooled[tid] = 0.f;
    }
  }
  __syncthreads();
  if (tid < EMB) {
    float e = proj_b[tid];
    const float* wr = proj_w + tid * FC;
    #pragma unroll 8
    for (int c = 0; c < FC; ++c) e = fmaf(wr[c], pooled[c], e);
    out_emb[(size_t)bp * EMB + tid] = e;
  }
}

extern "C" void kernel_launch(void* const* d_in, const int* in_sizes, int n_in,
                              void* d_out, int out_size, void* d_ws, size_t ws_size,
                              hipStream_t stream) {
  const float* x = (const float*)d_in[0];
  const float* aw1 = (const float*)d_in[25];
  const float* ab1 = (const float*)d_in[26];
  const float* ag  = (const float*)d_in[27];
  const float* abt = (const float*)d_in[28];
  const float* am  = (const float*)d_in[29];
  const float* av  = (const float*)d_in[30];
  const float* aw2 = (const float*)d_in[31];
  const float* ab2 = (const float*)d_in[32];
  const float* proj_w = (const float*)d_in[33];
  const float* proj_b = (const float*)d_in[34];

  float* wsf = (float*)d_ws;
  float* A    = wsf;                 // 120
  float* Bc   = wsf + 120;           // 120
  float* tcs  = wsf + 240;           // 1408
  float* tsn  = wsf + 1648;          // 1408
  float* comb = wsf + 3056;          // 140800
  int* ends_i = (int*)(wsf + 143856);       // 3200
  int* grid_i = (int*)(wsf + 147056);       // 3200
  unsigned short* pw = (unsigned short*)(wsf + 150256);     // 127488 ushorts
  unsigned short* feats = (unsigned short*)(wsf + 214000);  // 19.2M ushorts (38.4 MB)

  float* out      = (float*)d_out;
  float* out_emb  = out;             // 204800
  float* out_grid = out + 204800;    // 3200
  float* out_acti = out + 208000;    // 3200

  SetupArgs sa;
  for (int s = 0; s < 3; ++s) {
    sa.w1[s] = (const float*)d_in[1 + 8 * s];
    sa.b1[s] = (const float*)d_in[2 + 8 * s];
    sa.w2[s] = (const float*)d_in[3 + 8 * s];
    sa.b2[s] = (const float*)d_in[4 + 8 * s];
    sa.g[s]  = (const float*)d_in[5 + 8 * s];
    sa.bt[s] = (const float*)d_in[6 + 8 * s];
    sa.m[s]  = (const float*)d_in[7 + 8 * s];
    sa.v[s]  = (const float*)d_in[8 + 8 * s];
  }
  sa.pw = pw; sa.A = A; sa.Bc = Bc; sa.tcs = tcs; sa.tsn = tsn;

  setup_all<<<505, 256, 0, stream>>>(sa);
  stft_comb<<<B * CIN, 256, 0, stream>>>(x, tcs, tsn, comb);
  act_grid<<<B, 256, 0, stream>>>(comb, aw1, ab1, ag, abt, am, av, aw2, ab2,
                                  out_grid, out_acti, ends_i, grid_i);
  conv_mfma<<<dim3(40, B), 256, 0, stream>>>(x, pw, A, Bc, feats);
  pool_proj<<<B * P, 256, 0, stream>>>(feats, ends_i, grid_i, proj_w, proj_b, out_emb);
}

// Round 9
// 297.244 us; speedup vs baseline: 4.9862x; 1.0604x over previous
//
#include <hip/hip_runtime.h>
#include <hip/hip_bf16.h>
#include <math.h>
#include <string.h>

#define B 32
#define CIN 22
#define T 5000
#define EMB 64
#define P 100
#define HOP 25
#define OC 40
#define FC 120
#define NBIN 11   // rfft bins 5..15
#define NFR 200

#define TCH 128       // conv t-chunk
#define CROWS 176     // TCH + 24 halo each side
#define RSTRIDE 40    // ushorts per xs row (80 B = 20 dwords)

#define XPAD 5128     // reflect-padded x row: x[-64 .. 5063]

typedef unsigned short ushort_t;
typedef __attribute__((ext_vector_type(8))) short bf16x8;
typedef __attribute__((ext_vector_type(4))) float f32x4;

__device__ __forceinline__ unsigned short f2bf(float f) {
  unsigned u = __float_as_uint(f);
  unsigned r = (u + 0x7FFFu + ((u >> 16) & 1u)) >> 16;
  return (unsigned short)r;
}
__device__ __forceinline__ float bf2f(unsigned short u) {
  return __uint_as_float(((unsigned)u) << 16);
}
__device__ __forceinline__ float fast_elu(float y) {
  return y > 0.f ? y : (__builtin_amdgcn_exp2f(y * 1.44269504088896340736f) - 1.0f);
}
__device__ __forceinline__ unsigned pack2bf(float a, float b) {
  __hip_bfloat162 h = __float22bfloat162_rn(make_float2(a, b));
  unsigned u;
  memcpy(&u, &h, 4);
  return u;
}

// ---------------- K1: front = weight-pack + STFT + affine ----------------
struct FrontArgs {
  const float* w1[3]; const float* b1[3]; const float* w2[3]; const float* b2[3];
  const float* g[3];  const float* bt[3]; const float* m[3];  const float* v[3];
  const float* x;
  unsigned short* pw;
  float* A; float* Bc; float* comb;
};

__global__ __launch_bounds__(256) void front_all(FrontArgs args) {
  __shared__ float fsm[XPAD + NBIN * 128 * 2];   // 31.8 KB (stft blocks only)
  int bx = blockIdx.x;
  int tid = threadIdx.x;
  if (bx < 498) {
    // pack fused conv weights into MFMA A-fragment order
    int id = bx * 256 + tid;
    int s, KS, fbase, idl;
    if (id < 13824)       { s = 0; KS = 9;  fbase = 0;   idl = id; }
    else if (id < 52224)  { s = 1; KS = 25; fbase = 27;  idl = id - 13824; }
    else                  { s = 2; KS = 49; fbase = 102; idl = id - 52224; }
    int fi = idl >> 9, rem = idl & 511;
    int lane = rem >> 3, j = rem & 7;
    int k = fi / 3, ot = fi - k * 3;
    int m = lane & 15, h = ((lane >> 4) << 3) + j;
    int o = ot * 16 + m;
    float val = 0.f;
    if (h < CIN && o < OC) {
      const float* w1 = args.w1[s];
      const float* w2 = args.w2[s];
      for (int i = 0; i < OC; ++i)
        val = fmaf(w2[(o * OC + i) * CIN + h], w1[i * KS + k], val);
    }
    args.pw[(size_t)(fbase + fi) * 512 + rem] = f2bf(val);
  } else if (bx < 498 + B * CIN) {
    // STFT power -> comb, one block per (b,c) row; float twiddles computed in-block
    float* xsh = fsm;
    float* tw  = fsm + XPAD;
    int bc = bx - 498;
    const float* xr = args.x + (size_t)bc * T;
    const float TWO_PI_OVER_128 = 0.049087385212340517f;  // 2*pi/128
    for (int i = tid; i < NBIN * 128; i += 256) {
      int k = i / 128 + 5, n = i - (i / 128) * 128;
      float ang = -TWO_PI_OVER_128 * (float)(k * n);
      float win = 0.5f * (1.0f - __cosf(TWO_PI_OVER_128 * (float)n));
      tw[2 * i]     = __cosf(ang) * win;
      tw[2 * i + 1] = __sinf(ang) * win;
    }
    for (int i = tid; i < XPAD; i += 256) {
      int mm = i - 64;
      mm = (mm < 0) ? -mm : mm;
      mm = (mm >= T) ? (2 * T - 2 - mm) : mm;
      xsh[i] = xr[mm];
    }
    __syncthreads();
    int fr = tid;
    if (fr < NFR) {
      float cr[NBIN], ci[NBIN];
      #pragma unroll
      for (int k = 0; k < NBIN; ++k) { cr[k] = 0.f; ci[k] = 0.f; }
      const float* xw = xsh + fr * HOP;
      for (int n = 0; n < 128; ++n) {
        float xv = xw[n];
        const float* twn = tw + 2 * n;
        #pragma unroll
        for (int k = 0; k < NBIN; ++k) {
          float2 w = *reinterpret_cast<const float2*>(twn + 256 * k);
          cr[k] = fmaf(xv, w.x, cr[k]);
          ci[k] = fmaf(xv, w.y, ci[k]);
        }
      }
      float p[NBIN];
      #pragma unroll
      for (int k = 0; k < NBIN; ++k) p[k] = cr[k] * cr[k] + ci[k] * ci[k];
      float beta = 0.f;
      #pragma unroll
      for (int k = 2; k < NBIN; ++k) beta += p[k];
      args.comb[bc * NFR + fr] = 0.5f * (p[0] + p[1]) + beta * (1.f / 9.f);
    }
  } else {
    // BN/bias affine fold
    if (tid < 120) {
      int s = tid / 40, o = tid - s * 40;
      const float* w2 = args.w2[s];
      float sc = args.g[s][o] / sqrtf(args.v[s][o] + 1e-5f);
      float cc = args.b2[s][o];
      for (int i = 0; i < OC; ++i) {
        float sh = 0.f;
        for (int h = 0; h < CIN; ++h) sh += w2[(o * OC + i) * CIN + h];
        cc = fmaf(args.b1[s][i], sh, cc);
      }
      args.A[tid] = sc;
      args.Bc[tid] = cc * sc + (args.bt[s][o] - args.m[s][o] * sc);
    }
  }
}

// ---------------- K2: mid = conv_mfma blocks + act_grid blocks ----------------
__device__ __forceinline__ float wave_sum_f(float v) {
  #pragma unroll
  for (int off = 1; off < 64; off <<= 1) v += __shfl_xor(v, off);
  return v;
}
__device__ __forceinline__ int wave_sum_i(int v) {
  #pragma unroll
  for (int off = 1; off < 64; off <<= 1) v += __shfl_xor(v, off);
  return v;
}

struct MidSmem {
  union {
    struct {
      float cl[CIN * NFR];
      float actL[NFR];
      float aiL[P];
      float fL[P];
      int giL[P];
      int sI[P];
      float red;
    } a;
    unsigned short xs[CROWS * RSTRIDE];
  };
};

template <int KS, int FB, int SBASE>
__device__ __forceinline__ void scale_body(const unsigned short* __restrict__ xs,
                                           const unsigned short* __restrict__ pw,
                                           const float* __restrict__ Aff,
                                           const float* __restrict__ Bff,
                                           unsigned short* __restrict__ feats,
                                           int b, int t0, int wt0, int lane) {
  constexpr int PAD = (KS - 1) / 2;
  const int n = lane & 15, q = lane >> 4;
  f32x4 acc[3][2];
  #pragma unroll
  for (int ot = 0; ot < 3; ++ot)
    #pragma unroll
    for (int ti = 0; ti < 2; ++ti)
      acc[ot][ti] = (f32x4){0.f, 0.f, 0.f, 0.f};

  const unsigned short* pws = pw + (size_t)FB * 512 + lane * 8;
  #pragma unroll 1
  for (int k = 0; k < KS; ++k) {
    bf16x8 A0 = *(const bf16x8*)(pws + (size_t)(k * 3 + 0) * 512);
    bf16x8 A1 = *(const bf16x8*)(pws + (size_t)(k * 3 + 1) * 512);
    bf16x8 A2 = *(const bf16x8*)(pws + (size_t)(k * 3 + 2) * 512);
    int rbase = 24 - PAD + k + wt0 + n;
    #pragma unroll
    for (int ti = 0; ti < 2; ++ti) {
      bf16x8 Bf = *(const bf16x8*)(xs + (rbase + ti * 16) * RSTRIDE + q * 8);
      acc[0][ti] = __builtin_amdgcn_mfma_f32_16x16x32_bf16(A0, Bf, acc[0][ti], 0, 0, 0);
      acc[1][ti] = __builtin_amdgcn_mfma_f32_16x16x32_bf16(A1, Bf, acc[1][ti], 0, 0, 0);
      acc[2][ti] = __builtin_amdgcn_mfma_f32_16x16x32_bf16(A2, Bf, acc[2][ti], 0, 0, 0);
    }
  }
  #pragma unroll
  for (int ot = 0; ot < 3; ++ot) {
    int obase = ot * 16 + q * 4;
    if (obase < OC) {
      float Av0 = Aff[SBASE + obase + 0], Bv0 = Bff[SBASE + obase + 0];
      float Av1 = Aff[SBASE + obase + 1], Bv1 = Bff[SBASE + obase + 1];
      float Av2 = Aff[SBASE + obase + 2], Bv2 = Bff[SBASE + obase + 2];
      float Av3 = Aff[SBASE + obase + 3], Bv3 = Bff[SBASE + obase + 3];
      #pragma unroll
      for (int ti = 0; ti < 2; ++ti) {
        int tt = t0 + wt0 + ti * 16 + n;
        if (tt < T) {
          uint2 pk;
          pk.x = pack2bf(fast_elu(fmaf(acc[ot][ti][0], Av0, Bv0)),
                         fast_elu(fmaf(acc[ot][ti][1], Av1, Bv1)));
          pk.y = pack2bf(fast_elu(fmaf(acc[ot][ti][2], Av2, Bv2)),
                         fast_elu(fmaf(acc[ot][ti][3], Av3, Bv3)));
          *reinterpret_cast<uint2*>(feats + (size_t)(b * T + tt) * FC + SBASE + obase) = pk;
        }
      }
    }
  }
}

struct MidArgs {
  const float* x;
  const unsigned short* pw;
  const float* Aff; const float* Bff;
  unsigned short* feats;
  const float* comb;
  const float* aw1; const float* ab1;
  const float* ag;  const float* abt;
  const float* am;  const float* av;
  const float* aw2; const float* ab2;
  float* out_grid; float* out_acti;
  int* ends_i; int* grid_i;
};

__global__ __launch_bounds__(256) void mid_all(MidArgs args) {
  __shared__ MidSmem sm;
  int bx = blockIdx.x;
  int tid = threadIdx.x;
  if (bx < 40 * B) {
    // ---- conv ----
    int b = bx / 40, t0 = (bx - b * 40) * TCH;
    for (int idx = tid; idx < CIN * CROWS; idx += 256) {
      int h = idx / CROWS, tl = idx - h * CROWS;
      int gt = t0 - 24 + tl;
      float v = (gt >= 0 && gt < T) ? args.x[(size_t)(b * CIN + h) * T + gt] : 0.f;
      sm.xs[tl * RSTRIDE + h] = f2bf(v);
    }
    for (int idx = tid; idx < 10 * CROWS; idx += 256) {
      int c = idx / CROWS, tl = idx - c * CROWS;
      sm.xs[tl * RSTRIDE + 22 + c] = 0;
    }
    __syncthreads();
    int wv = tid >> 6, lane = tid & 63;
    int wt0 = wv * 32;
    scale_body<9, 0, 0>(sm.xs, args.pw, args.Aff, args.Bff, args.feats, b, t0, wt0, lane);
    scale_body<25, 27, 40>(sm.xs, args.pw, args.Aff, args.Bff, args.feats, b, t0, wt0, lane);
    scale_body<49, 102, 80>(sm.xs, args.pw, args.Aff, args.Bff, args.feats, b, t0, wt0, lane);
  } else {
    // ---- act_grid ----
    int b = bx - 40 * B;
    for (int i = tid; i < CIN * NFR; i += 256) sm.a.cl[i] = args.comb[b * CIN * NFR + i];
    __syncthreads();
    int t = tid;
    if (t < NFR) {
      float z = args.ab2[0];
      for (int o = 0; o < 11; ++o) {
        float s = args.ab1[o];
        for (int i = 0; i < CIN; ++i) {
          const float* wr = args.aw1 + o * 66 + i * 3;
          const float* crow = sm.a.cl + i * NFR;
          if (t > 0)       s = fmaf(wr[0], crow[t - 1], s);
          s = fmaf(wr[1], crow[t], s);
          if (t < NFR - 1) s = fmaf(wr[2], crow[t + 1], s);
        }
        float rs = 1.0f / sqrtf(args.av[o] + 1e-5f);
        float y = (s - args.am[o]) * rs * args.ag[o] + args.abt[o];
        y = fmaxf(y, 0.f);
        z = fmaf(args.aw2[o], y, z);
      }
      sm.a.actL[t] = 1.f / (1.f + expf(-z));
    }
    __syncthreads();
    if (t < P) {
      float ai = 0.5f * (sm.a.actL[2 * t] + sm.a.actL[2 * t + 1]);
      sm.a.aiL[t] = ai;
      args.out_acti[b * P + t] = ai;
      sm.a.fL[t] = 1.f / (ai + 1e-6f);
    }
    __syncthreads();
    if (t < 64) {
      float v = sm.a.fL[t] + ((t + 64 < P) ? sm.a.fL[t + 64] : 0.f);
      v = wave_sum_f(v);
      if (t == 0) sm.a.red = v;
    }
    __syncthreads();
    float sw = sm.a.red;
    if (t < P) {
      float gg = (sm.a.fL[t] / sw) * 5000.f;
      gg = fminf(fmaxf(gg, 10.f), 100.f);
      sm.a.fL[t] = gg;
    }
    __syncthreads();
    if (t < 64) {
      float v = sm.a.fL[t] + ((t + 64 < P) ? sm.a.fL[t + 64] : 0.f);
      v = wave_sum_f(v);
      if (t == 0) sm.a.red = v;
    }
    __syncthreads();
    float r = 5000.f / sm.a.red;
    if (t < P) sm.a.giL[t] = (int)rintf(sm.a.fL[t] * r);
    __syncthreads();
    if (t < 64) {
      int v = sm.a.giL[t] + ((t + 64 < P) ? sm.a.giL[t + 64] : 0);
      v = wave_sum_i(v);
      if (t == 0) sm.a.red = __int_as_float(v);
    }
    __syncthreads();
    if (t == P - 1) sm.a.giL[P - 1] += 5000 - __float_as_int(sm.a.red);
    __syncthreads();
    if (t < P) sm.a.giL[t] = min(max(sm.a.giL[t], 10), 100);
    __syncthreads();
    if (t < 64) {
      int v = sm.a.giL[t] + ((t + 64 < P) ? sm.a.giL[t + 64] : 0);
      v = wave_sum_i(v);
      if (t == 0) sm.a.red = __int_as_float(v);
    }
    __syncthreads();
    if (t == P - 1) sm.a.giL[P - 1] += 5000 - __float_as_int(sm.a.red);
    __syncthreads();
    if (t < P) sm.a.sI[t] = max(sm.a.giL[t], 10);
    __syncthreads();
    #pragma unroll
    for (int off = 1; off < P; off <<= 1) {
      int v = 0;
      if (t < P && t >= off) v = sm.a.sI[t - off];
      __syncthreads();
      if (t < P) sm.a.sI[t] += v;
      __syncthreads();
    }
    if (t < P) {
      int g = max(sm.a.giL[t], 10);
      args.out_grid[b * P + t] = (float)g;
      args.grid_i[b * P + t] = g;
      args.ends_i[b * P + t] = sm.a.sI[t];
    }
  }
}

// ---------------- K3: ragged avg+max pool + projection ----------------
__global__ __launch_bounds__(256) void pool_proj(const unsigned short* __restrict__ feats,
                                                 const int* __restrict__ ends_i,
                                                 const int* __restrict__ grid_i,
                                                 const float* __restrict__ proj_w,
                                                 const float* __restrict__ proj_b,
                                                 float* __restrict__ out_emb) {
  int bp = blockIdx.x;
  int b = bp / P;
  int end = ends_i[bp];
  int gr = grid_i[bp];
  int start = end - gr;
  __shared__ float lds_s[8 * FC];
  __shared__ float lds_m[8 * FC];
  __shared__ float pooled[FC];
  int tid = threadIdx.x;
  bool valid = (end <= T);
  int g = tid % 30;     // channel quad
  int r = tid / 30;     // time slice 0..8 (r==8 -> idle)
  if (valid && r < 8) {
    float s0 = 0.f, s1 = 0.f, s2 = 0.f, s3 = 0.f;
    float m0 = -INFINITY, m1 = -INFINITY, m2 = -INFINITY, m3 = -INFINITY;
    const unsigned short* base = feats + (size_t)(b * T + start) * FC + g * 4;
    for (int i = r; i < gr; i += 8) {
      uint2 u = *reinterpret_cast<const uint2*>(base + (size_t)i * FC);
      float v0 = bf2f((unsigned short)(u.x & 0xffffu));
      float v1 = bf2f((unsigned short)(u.x >> 16));
      float v2 = bf2f((unsigned short)(u.y & 0xffffu));
      float v3 = bf2f((unsigned short)(u.y >> 16));
      s0 += v0; s1 += v1; s2 += v2; s3 += v3;
      m0 = fmaxf(m0, v0); m1 = fmaxf(m1, v1); m2 = fmaxf(m2, v2); m3 = fmaxf(m3, v3);
    }
    lds_s[r * FC + g * 4 + 0] = s0; lds_s[r * FC + g * 4 + 1] = s1;
    lds_s[r * FC + g * 4 + 2] = s2; lds_s[r * FC + g * 4 + 3] = s3;
    lds_m[r * FC + g * 4 + 0] = m0; lds_m[r * FC + g * 4 + 1] = m1;
    lds_m[r * FC + g * 4 + 2] = m2; lds_m[r * FC + g * 4 + 3] = m3;
  }
  __syncthreads();
  if (tid < FC) {
    if (valid) {
      float s = 0.f, mx = -INFINITY;
      #pragma unroll
      for (int rr = 0; rr < 8; ++rr) {
        s += lds_s[rr * FC + tid];
        mx = fmaxf(mx, lds_m[rr * FC + tid]);
      }
      pooled[tid] = s / (float)gr + mx;
    } else {
      pooled[tid] = 0.f;
    }
  }
  __syncthreads();
  if (tid < EMB) {
    float e = proj_b[tid];
    const float* wr = proj_w + tid * FC;
    #pragma unroll 8
    for (int c = 0; c < FC; ++c) e = fmaf(wr[c], pooled[c], e);
    out_emb[(size_t)bp * EMB + tid] = e;
  }
}

extern "C" void kernel_launch(void* const* d_in, const int* in_sizes, int n_in,
                              void* d_out, int out_size, void* d_ws, size_t ws_size,
                              hipStream_t stream) {
  const float* x = (const float*)d_in[0];
  const float* aw1 = (const float*)d_in[25];
  const float* ab1 = (const float*)d_in[26];
  const float* ag  = (const float*)d_in[27];
  const float* abt = (const float*)d_in[28];
  const float* am  = (const float*)d_in[29];
  const float* av  = (const float*)d_in[30];
  const float* aw2 = (const float*)d_in[31];
  const float* ab2 = (const float*)d_in[32];
  const float* proj_w = (const float*)d_in[33];
  const float* proj_b = (const float*)d_in[34];

  float* wsf = (float*)d_ws;
  float* A    = wsf;                 // 120
  float* Bc   = wsf + 120;           // 120
  float* comb = wsf + 3056;          // 140800
  int* ends_i = (int*)(wsf + 143856);       // 3200
  int* grid_i = (int*)(wsf + 147056);       // 3200
  unsigned short* pw = (unsigned short*)(wsf + 150256);     // 127488 ushorts
  unsigned short* feats = (unsigned short*)(wsf + 214000);  // 19.2M ushorts (38.4 MB)

  float* out      = (float*)d_out;
  float* out_emb  = out;             // 204800
  float* out_grid = out + 204800;    // 3200
  float* out_acti = out + 208000;    // 3200

  FrontArgs fa;
  MidArgs ma;
  for (int s = 0; s < 3; ++s) {
    fa.w1[s] = (const float*)d_in[1 + 8 * s];
    fa.b1[s] = (const float*)d_in[2 + 8 * s];
    fa.w2[s] = (const float*)d_in[3 + 8 * s];
    fa.b2[s] = (const float*)d_in[4 + 8 * s];
    fa.g[s]  = (const float*)d_in[5 + 8 * s];
    fa.bt[s] = (const float*)d_in[6 + 8 * s];
    fa.m[s]  = (const float*)d_in[7 + 8 * s];
    fa.v[s]  = (const float*)d_in[8 + 8 * s];
  }
  fa.x = x; fa.pw = pw; fa.A = A; fa.Bc = Bc; fa.comb = comb;

  ma.x = x; ma.pw = pw; ma.Aff = A; ma.Bff = Bc; ma.feats = feats;
  ma.comb = comb; ma.aw1 = aw1; ma.ab1 = ab1; ma.ag = ag; ma.abt = abt;
  ma.am = am; ma.av = av; ma.aw2 = aw2; ma.ab2 = ab2;
  ma.out_grid = out_grid; ma.out_acti = out_acti;
  ma.ends_i = ends_i; ma.grid_i = grid_i;

  front_all<<<498 + B * CIN + 1, 256, 0, stream>>>(fa);
  mid_all<<<40 * B + B, 256, 0, stream>>>(ma);
  pool_proj<<<B * P, 256, 0, stream>>>(feats, ends_i, grid_i, proj_w, proj_b, out_emb);
}

// Round 10
// 260.330 us; speedup vs baseline: 5.6933x; 1.1418x over previous
//
#include <hip/hip_runtime.h>
#include <hip/hip_bf16.h>
#include <math.h>
#include <string.h>

#define B 32
#define CIN 22
#define T 5000
#define EMB 64
#define P 100
#define HOP 25
#define OC 40
#define FC 120
#define NBIN 11   // rfft bins 5..15
#define NFR 200

#define TCH 128       // conv t-chunk
#define CROWS 176     // TCH + 24 halo each side
#define RSTRIDE 40    // ushorts per xs row (80 B = 20 dwords)

#define XPAD 5128     // reflect-padded x row: x[-64 .. 5063]

typedef unsigned short ushort_t;
typedef __attribute__((ext_vector_type(8))) short bf16x8;
typedef __attribute__((ext_vector_type(4))) float f32x4;

__device__ __forceinline__ unsigned short f2bf(float f) {
  unsigned u = __float_as_uint(f);
  unsigned r = (u + 0x7FFFu + ((u >> 16) & 1u)) >> 16;
  return (unsigned short)r;
}
__device__ __forceinline__ float bf2f(unsigned short u) {
  return __uint_as_float(((unsigned)u) << 16);
}
__device__ __forceinline__ float fast_elu(float y) {
  return y > 0.f ? y : (__builtin_amdgcn_exp2f(y * 1.44269504088896340736f) - 1.0f);
}
__device__ __forceinline__ unsigned pack2bf(float a, float b) {
  __hip_bfloat162 h = __float22bfloat162_rn(make_float2(a, b));
  unsigned u;
  memcpy(&u, &h, 4);
  return u;
}

// ---------------- K1: front = weight-pack + STFT + affine ----------------
struct FrontArgs {
  const float* w1[3]; const float* b1[3]; const float* w2[3]; const float* b2[3];
  const float* g[3];  const float* bt[3]; const float* m[3];  const float* v[3];
  const float* x;
  unsigned short* pw;
  float* A; float* Bc; float* comb;
};

__global__ __launch_bounds__(256) void front_all(FrontArgs args) {
  __shared__ float fsm[XPAD + NBIN * 128 * 2];   // 31.8 KB (stft blocks only)
  int bx = blockIdx.x;
  int tid = threadIdx.x;
  if (bx < 498) {
    // pack fused conv weights into MFMA A-fragment order
    int id = bx * 256 + tid;
    int s, KS, fbase, idl;
    if (id < 13824)       { s = 0; KS = 9;  fbase = 0;   idl = id; }
    else if (id < 52224)  { s = 1; KS = 25; fbase = 27;  idl = id - 13824; }
    else                  { s = 2; KS = 49; fbase = 102; idl = id - 52224; }
    int fi = idl >> 9, rem = idl & 511;
    int lane = rem >> 3, j = rem & 7;
    int k = fi / 3, ot = fi - k * 3;
    int m = lane & 15, h = ((lane >> 4) << 3) + j;
    int o = ot * 16 + m;
    float val = 0.f;
    if (h < CIN && o < OC) {
      const float* w1 = args.w1[s];
      const float* w2 = args.w2[s];
      for (int i = 0; i < OC; ++i)
        val = fmaf(w2[(o * OC + i) * CIN + h], w1[i * KS + k], val);
    }
    args.pw[(size_t)(fbase + fi) * 512 + rem] = f2bf(val);
  } else if (bx < 498 + B * CIN) {
    // STFT power -> comb, one block per (b,c) row; float twiddles computed in-block
    float* xsh = fsm;
    float* tw  = fsm + XPAD;
    int bc = bx - 498;
    const float* xr = args.x + (size_t)bc * T;
    const float TWO_PI_OVER_128 = 0.049087385212340517f;  // 2*pi/128
    for (int i = tid; i < NBIN * 128; i += 256) {
      int k = i / 128 + 5, n = i - (i / 128) * 128;
      float ang = -TWO_PI_OVER_128 * (float)(k * n);
      float win = 0.5f * (1.0f - __cosf(TWO_PI_OVER_128 * (float)n));
      tw[2 * i]     = __cosf(ang) * win;
      tw[2 * i + 1] = __sinf(ang) * win;
    }
    for (int i = tid; i < XPAD; i += 256) {
      int mm = i - 64;
      mm = (mm < 0) ? -mm : mm;
      mm = (mm >= T) ? (2 * T - 2 - mm) : mm;
      xsh[i] = xr[mm];
    }
    __syncthreads();
    int fr = tid;
    if (fr < NFR) {
      float cr[NBIN], ci[NBIN];
      #pragma unroll
      for (int k = 0; k < NBIN; ++k) { cr[k] = 0.f; ci[k] = 0.f; }
      const float* xw = xsh + fr * HOP;
      for (int n = 0; n < 128; ++n) {
        float xv = xw[n];
        const float* twn = tw + 2 * n;
        #pragma unroll
        for (int k = 0; k < NBIN; ++k) {
          float2 w = *reinterpret_cast<const float2*>(twn + 256 * k);
          cr[k] = fmaf(xv, w.x, cr[k]);
          ci[k] = fmaf(xv, w.y, ci[k]);
        }
      }
      float p[NBIN];
      #pragma unroll
      for (int k = 0; k < NBIN; ++k) p[k] = cr[k] * cr[k] + ci[k] * ci[k];
      float beta = 0.f;
      #pragma unroll
      for (int k = 2; k < NBIN; ++k) beta += p[k];
      args.comb[bc * NFR + fr] = 0.5f * (p[0] + p[1]) + beta * (1.f / 9.f);
    }
  } else {
    // BN/bias affine fold
    if (tid < 120) {
      int s = tid / 40, o = tid - s * 40;
      const float* w2 = args.w2[s];
      float sc = args.g[s][o] / sqrtf(args.v[s][o] + 1e-5f);
      float cc = args.b2[s][o];
      for (int i = 0; i < OC; ++i) {
        float sh = 0.f;
        for (int h = 0; h < CIN; ++h) sh += w2[(o * OC + i) * CIN + h];
        cc = fmaf(args.b1[s][i], sh, cc);
      }
      args.A[tid] = sc;
      args.Bc[tid] = cc * sc + (args.bt[s][o] - args.m[s][o] * sc);
    }
  }
}

// ---------------- K2: mid = act_grid blocks FIRST, then conv_mfma blocks ----------------
__device__ __forceinline__ float wave_sum_f(float v) {
  #pragma unroll
  for (int off = 1; off < 64; off <<= 1) v += __shfl_xor(v, off);
  return v;
}
__device__ __forceinline__ int wave_sum_i(int v) {
  #pragma unroll
  for (int off = 1; off < 64; off <<= 1) v += __shfl_xor(v, off);
  return v;
}

struct MidSmem {
  union {
    struct {
      float cl[CIN * NFR];
      float actL[NFR];
      float aiL[P];
      float fL[P];
      int giL[P];
      int sI[P];
      float red;
    } a;
    unsigned short xs[CROWS * RSTRIDE];
  };
};

template <int KS, int FB, int SBASE>
__device__ __forceinline__ void scale_body(const unsigned short* __restrict__ xs,
                                           const unsigned short* __restrict__ pw,
                                           const float* __restrict__ Aff,
                                           const float* __restrict__ Bff,
                                           unsigned short* __restrict__ feats,
                                           int b, int t0, int wt0, int lane) {
  constexpr int PAD = (KS - 1) / 2;
  const int n = lane & 15, q = lane >> 4;
  f32x4 acc[3][2];
  #pragma unroll
  for (int ot = 0; ot < 3; ++ot)
    #pragma unroll
    for (int ti = 0; ti < 2; ++ti)
      acc[ot][ti] = (f32x4){0.f, 0.f, 0.f, 0.f};

  const unsigned short* pws = pw + (size_t)FB * 512 + lane * 8;
  #pragma unroll 1
  for (int k = 0; k < KS; ++k) {
    bf16x8 A0 = *(const bf16x8*)(pws + (size_t)(k * 3 + 0) * 512);
    bf16x8 A1 = *(const bf16x8*)(pws + (size_t)(k * 3 + 1) * 512);
    bf16x8 A2 = *(const bf16x8*)(pws + (size_t)(k * 3 + 2) * 512);
    int rbase = 24 - PAD + k + wt0 + n;
    #pragma unroll
    for (int ti = 0; ti < 2; ++ti) {
      bf16x8 Bf = *(const bf16x8*)(xs + (rbase + ti * 16) * RSTRIDE + q * 8);
      acc[0][ti] = __builtin_amdgcn_mfma_f32_16x16x32_bf16(A0, Bf, acc[0][ti], 0, 0, 0);
      acc[1][ti] = __builtin_amdgcn_mfma_f32_16x16x32_bf16(A1, Bf, acc[1][ti], 0, 0, 0);
      acc[2][ti] = __builtin_amdgcn_mfma_f32_16x16x32_bf16(A2, Bf, acc[2][ti], 0, 0, 0);
    }
  }
  #pragma unroll
  for (int ot = 0; ot < 3; ++ot) {
    int obase = ot * 16 + q * 4;
    if (obase < OC) {
      float Av0 = Aff[SBASE + obase + 0], Bv0 = Bff[SBASE + obase + 0];
      float Av1 = Aff[SBASE + obase + 1], Bv1 = Bff[SBASE + obase + 1];
      float Av2 = Aff[SBASE + obase + 2], Bv2 = Bff[SBASE + obase + 2];
      float Av3 = Aff[SBASE + obase + 3], Bv3 = Bff[SBASE + obase + 3];
      #pragma unroll
      for (int ti = 0; ti < 2; ++ti) {
        int tt = t0 + wt0 + ti * 16 + n;
        if (tt < T) {
          uint2 pk;
          pk.x = pack2bf(fast_elu(fmaf(acc[ot][ti][0], Av0, Bv0)),
                         fast_elu(fmaf(acc[ot][ti][1], Av1, Bv1)));
          pk.y = pack2bf(fast_elu(fmaf(acc[ot][ti][2], Av2, Bv2)),
                         fast_elu(fmaf(acc[ot][ti][3], Av3, Bv3)));
          *reinterpret_cast<uint2*>(feats + (size_t)(b * T + tt) * FC + SBASE + obase) = pk;
        }
      }
    }
  }
}

struct MidArgs {
  const float* x;
  const unsigned short* pw;
  const float* Aff; const float* Bff;
  unsigned short* feats;
  const float* comb;
  const float* aw1; const float* ab1;
  const float* ag;  const float* abt;
  const float* am;  const float* av;
  const float* aw2; const float* ab2;
  float* out_grid; float* out_acti;
  int* ends_i; int* grid_i;
};

__global__ __launch_bounds__(256) void mid_all(MidArgs args) {
  __shared__ MidSmem sm;
  int bx = blockIdx.x;
  int tid = threadIdx.x;
  if (bx >= B) {
    // ---- conv ----
    int cx = bx - B;
    int b = cx / 40, t0 = (cx - b * 40) * TCH;
    for (int idx = tid; idx < CIN * CROWS; idx += 256) {
      int h = idx / CROWS, tl = idx - h * CROWS;
      int gt = t0 - 24 + tl;
      float v = (gt >= 0 && gt < T) ? args.x[(size_t)(b * CIN + h) * T + gt] : 0.f;
      sm.xs[tl * RSTRIDE + h] = f2bf(v);
    }
    for (int idx = tid; idx < 10 * CROWS; idx += 256) {
      int c = idx / CROWS, tl = idx - c * CROWS;
      sm.xs[tl * RSTRIDE + 22 + c] = 0;
    }
    __syncthreads();
    int wv = tid >> 6, lane = tid & 63;
    int wt0 = wv * 32;
    scale_body<9, 0, 0>(sm.xs, args.pw, args.Aff, args.Bff, args.feats, b, t0, wt0, lane);
    scale_body<25, 27, 40>(sm.xs, args.pw, args.Aff, args.Bff, args.feats, b, t0, wt0, lane);
    scale_body<49, 102, 80>(sm.xs, args.pw, args.Aff, args.Bff, args.feats, b, t0, wt0, lane);
  } else {
    // ---- act_grid ----
    int b = bx;
    for (int i = tid; i < CIN * NFR; i += 256) sm.a.cl[i] = args.comb[b * CIN * NFR + i];
    __syncthreads();
    int t = tid;
    if (t < NFR) {
      float z = args.ab2[0];
      for (int o = 0; o < 11; ++o) {
        float s = args.ab1[o];
        for (int i = 0; i < CIN; ++i) {
          const float* wr = args.aw1 + o * 66 + i * 3;
          const float* crow = sm.a.cl + i * NFR;
          if (t > 0)       s = fmaf(wr[0], crow[t - 1], s);
          s = fmaf(wr[1], crow[t], s);
          if (t < NFR - 1) s = fmaf(wr[2], crow[t + 1], s);
        }
        float rs = 1.0f / sqrtf(args.av[o] + 1e-5f);
        float y = (s - args.am[o]) * rs * args.ag[o] + args.abt[o];
        y = fmaxf(y, 0.f);
        z = fmaf(args.aw2[o], y, z);
      }
      sm.a.actL[t] = 1.f / (1.f + expf(-z));
    }
    __syncthreads();
    if (t < P) {
      float ai = 0.5f * (sm.a.actL[2 * t] + sm.a.actL[2 * t + 1]);
      sm.a.aiL[t] = ai;
      args.out_acti[b * P + t] = ai;
      sm.a.fL[t] = 1.f / (ai + 1e-6f);
    }
    __syncthreads();
    if (t < 64) {
      float v = sm.a.fL[t] + ((t + 64 < P) ? sm.a.fL[t + 64] : 0.f);
      v = wave_sum_f(v);
      if (t == 0) sm.a.red = v;
    }
    __syncthreads();
    float sw = sm.a.red;
    if (t < P) {
      float gg = (sm.a.fL[t] / sw) * 5000.f;
      gg = fminf(fmaxf(gg, 10.f), 100.f);
      sm.a.fL[t] = gg;
    }
    __syncthreads();
    if (t < 64) {
      float v = sm.a.fL[t] + ((t + 64 < P) ? sm.a.fL[t + 64] : 0.f);
      v = wave_sum_f(v);
      if (t == 0) sm.a.red = v;
    }
    __syncthreads();
    float r = 5000.f / sm.a.red;
    if (t < P) sm.a.giL[t] = (int)rintf(sm.a.fL[t] * r);
    __syncthreads();
    if (t < 64) {
      int v = sm.a.giL[t] + ((t + 64 < P) ? sm.a.giL[t + 64] : 0);
      v = wave_sum_i(v);
      if (t == 0) sm.a.red = __int_as_float(v);
    }
    __syncthreads();
    if (t == P - 1) sm.a.giL[P - 1] += 5000 - __float_as_int(sm.a.red);
    __syncthreads();
    if (t < P) sm.a.giL[t] = min(max(sm.a.giL[t], 10), 100);
    __syncthreads();
    if (t < 64) {
      int v = sm.a.giL[t] + ((t + 64 < P) ? sm.a.giL[t + 64] : 0);
      v = wave_sum_i(v);
      if (t == 0) sm.a.red = __int_as_float(v);
    }
    __syncthreads();
    if (t == P - 1) sm.a.giL[P - 1] += 5000 - __float_as_int(sm.a.red);
    __syncthreads();
    if (t < P) sm.a.sI[t] = max(sm.a.giL[t], 10);
    __syncthreads();
    #pragma unroll
    for (int off = 1; off < P; off <<= 1) {
      int v = 0;
      if (t < P && t >= off) v = sm.a.sI[t - off];
      __syncthreads();
      if (t < P) sm.a.sI[t] += v;
      __syncthreads();
    }
    if (t < P) {
      int g = max(sm.a.giL[t], 10);
      args.out_grid[b * P + t] = (float)g;
      args.grid_i[b * P + t] = g;
      args.ends_i[b * P + t] = sm.a.sI[t];
    }
  }
}

// ---------------- K3: ragged avg+max pool + projection ----------------
// 256 threads = 15 channel-octets (uint4) x 16 time-slices (+16 idle)
__global__ __launch_bounds__(256) void pool_proj(const unsigned short* __restrict__ feats,
                                                 const int* __restrict__ ends_i,
                                                 const int* __restrict__ grid_i,
                                                 const float* __restrict__ proj_w,
                                                 const float* __restrict__ proj_b,
                                                 float* __restrict__ out_emb) {
  int bp = blockIdx.x;
  int b = bp / P;
  int end = ends_i[bp];
  int gr = grid_i[bp];
  int start = end - gr;
  __shared__ float lds_s[16 * FC];
  __shared__ float lds_m[16 * FC];
  __shared__ float pooled[FC];
  int tid = threadIdx.x;
  bool valid = (end <= T);
  int g = tid % 15;     // channel octet (8 bf16 = 16 B)
  int r = tid / 15;     // time slice 0..16 (r==17 region idle)
  if (valid && r < 16) {
    float s[8], m[8];
    #pragma unroll
    for (int j = 0; j < 8; ++j) { s[j] = 0.f; m[j] = -INFINITY; }
    const unsigned short* base = feats + (size_t)(b * T + start) * FC + g * 8;
    for (int i = r; i < gr; i += 16) {
      uint4 u = *reinterpret_cast<const uint4*>(base + (size_t)i * FC);
      unsigned w[4] = {u.x, u.y, u.z, u.w};
      #pragma unroll
      for (int j = 0; j < 4; ++j) {
        float v0 = bf2f((unsigned short)(w[j] & 0xffffu));
        float v1 = bf2f((unsigned short)(w[j] >> 16));
        s[2 * j] += v0; s[2 * j + 1] += v1;
        m[2 * j] = fmaxf(m[2 * j], v0); m[2 * j + 1] = fmaxf(m[2 * j + 1], v1);
      }
    }
    #pragma unroll
    for (int j = 0; j < 8; ++j) {
      lds_s[r * FC + g * 8 + j] = s[j];
      lds_m[r * FC + g * 8 + j] = m[j];
    }
  }
  __syncthreads();
  if (tid < FC) {
    if (valid) {
      float s = 0.f, mx = -INFINITY;
      #pragma unroll
      for (int rr = 0; rr < 16; ++rr) {
        s += lds_s[rr * FC + tid];
        mx = fmaxf(mx, lds_m[rr * FC + tid]);
      }
      pooled[tid] = s / (float)gr + mx;
    } else {
      pooled[tid] = 0.f;
    }
  }
  __syncthreads();
  if (tid < EMB) {
    float e = proj_b[tid];
    const float* wr = proj_w + tid * FC;
    #pragma unroll 8
    for (int c = 0; c < FC; ++c) e = fmaf(wr[c], pooled[c], e);
    out_emb[(size_t)bp * EMB + tid] = e;
  }
}

extern "C" void kernel_launch(void* const* d_in, const int* in_sizes, int n_in,
                              void* d_out, int out_size, void* d_ws, size_t ws_size,
                              hipStream_t stream) {
  const float* x = (const float*)d_in[0];
  const float* aw1 = (const float*)d_in[25];
  const float* ab1 = (const float*)d_in[26];
  const float* ag  = (const float*)d_in[27];
  const float* abt = (const float*)d_in[28];
  const float* am  = (const float*)d_in[29];
  const float* av  = (const float*)d_in[30];
  const float* aw2 = (const float*)d_in[31];
  const float* ab2 = (const float*)d_in[32];
  const float* proj_w = (const float*)d_in[33];
  const float* proj_b = (const float*)d_in[34];

  float* wsf = (float*)d_ws;
  float* A    = wsf;                 // 120
  float* Bc   = wsf + 120;           // 120
  float* comb = wsf + 3056;          // 140800
  int* ends_i = (int*)(wsf + 143856);       // 3200
  int* grid_i = (int*)(wsf + 147056);       // 3200
  unsigned short* pw = (unsigned short*)(wsf + 150256);     // 127488 ushorts
  unsigned short* feats = (unsigned short*)(wsf + 214000);  // 19.2M ushorts (38.4 MB)

  float* out      = (float*)d_out;
  float* out_emb  = out;             // 204800
  float* out_grid = out + 204800;    // 3200
  float* out_acti = out + 208000;    // 3200

  FrontArgs fa;
  MidArgs ma;
  for (int s = 0; s < 3; ++s) {
    fa.w1[s] = (const float*)d_in[1 + 8 * s];
    fa.b1[s] = (const float*)d_in[2 + 8 * s];
    fa.w2[s] = (const float*)d_in[3 + 8 * s];
    fa.b2[s] = (const float*)d_in[4 + 8 * s];
    fa.g[s]  = (const float*)d_in[5 + 8 * s];
    fa.bt[s] = (const float*)d_in[6 + 8 * s];
    fa.m[s]  = (const float*)d_in[7 + 8 * s];
    fa.v[s]  = (const float*)d_in[8 + 8 * s];
  }
  fa.x = x; fa.pw = pw; fa.A = A; fa.Bc = Bc; fa.comb = comb;

  ma.x = x; ma.pw = pw; ma.Aff = A; ma.Bff = Bc; ma.feats = feats;
  ma.comb = comb; ma.aw1 = aw1; ma.ab1 = ab1; ma.ag = ag; ma.abt = abt;
  ma.am = am; ma.av = av; ma.aw2 = aw2; ma.ab2 = ab2;
  ma.out_grid = out_grid; ma.out_acti = out_acti;
  ma.ends_i = ends_i; ma.grid_i = grid_i;

  front_all<<<498 + B * CIN + 1, 256, 0, stream>>>(fa);
  mid_all<<<B + 40 * B, 256, 0, stream>>>(ma);
  pool_proj<<<B * P, 256, 0, stream>>>(feats, ends_i, grid_i, proj_w, proj_b, out_emb);
}